// Round 4
// baseline (2798.675 us; speedup 1.0000x reference)
//
#include <hip/hip_runtime.h>
#include <hip/hip_bf16.h>

typedef __bf16 bf16;
typedef __attribute__((ext_vector_type(8))) __bf16 bf16x8;
typedef __attribute__((ext_vector_type(4))) float f32x4;

#define MFMA16(a, b, c) __builtin_amdgcn_mfma_f32_16x16x32_bf16((a), (b), (c), 0, 0, 0)

#define SYNC_VM(N) do { asm volatile("s_waitcnt vmcnt(" #N ")" ::: "memory"); \
    __builtin_amdgcn_s_barrier(); __builtin_amdgcn_sched_barrier(0); } while (0)
#define SYNC_LGKM() do { asm volatile("s_waitcnt lgkmcnt(0)" ::: "memory"); \
    __builtin_amdgcn_s_barrier(); __builtin_amdgcn_sched_barrier(0); } while (0)

__device__ __forceinline__ void async16(const bf16* g, bf16* l) {
    __builtin_amdgcn_global_load_lds((__attribute__((address_space(1))) void*)(g),
                                     (__attribute__((address_space(3))) void*)(l), 16, 0, 0);
}

// Bijective XCD-chunked swizzle (m204).
__device__ __forceinline__ void xcd_swizzle(int& bx, int& by, int& bz) {
    const int gx = gridDim.x, gy = gridDim.y;
    const int nwg = gx * gy * gridDim.z;
    const int lin = blockIdx.x + gx * (blockIdx.y + gy * blockIdx.z);
    const int xcd = lin & 7, seq = lin >> 3;
    const int q = nwg >> 3, r = nwg & 7;
    const int nl = (xcd < r ? xcd * (q + 1) : r * (q + 1) + (xcd - r) * q) + seq;
    bx = nl % gx;
    const int t = nl / gx;
    by = t % gy;
    bz = t / gy;
}

// ---------------------------------------------------------------------------
// Single-wave GEMM: block = 64 threads = ONE wave owning a 64x64 C-tile.
// NO barriers anywhere: the wave's in-order issue + vmcnt is the only sync.
//   - double-buffered LDS (2 x (4KB A + 4KB B) = 16 KB -> 10 blocks/CU)
//   - per iter: vmcnt(8) [tile kt landed, kt+1 in flight] -> 8 ds_read_b128
//     -> 16 MFMA -> restage tile kt+2 into buf[cur] (safe: MFMA issue implies
//     the compiler's lgkm waits for this buffer's ds_reads already passed).
//   - T2 chunk-XOR swizzle identical to the verified r3 layout:
//     stage source col-chunk = (c&3) ^ ((row>>1)&3); read chF = quad ^ ((l15>>1)&3).
// MODE 0: bf16 out + 3-segment bias (QKV). MODE 1: f32 partial out (split-K<=3).
// ---------------------------------------------------------------------------
template <int MODE>
__global__ __launch_bounds__(64) void gemm1w_kernel(
    const bf16* __restrict__ A, const bf16* __restrict__ WT,
    const float* __restrict__ b0, const float* __restrict__ b1, const float* __restrict__ b2,
    int s1, int s2,
    float* __restrict__ o0, float* __restrict__ o1, float* __restrict__ o2,
    bf16* __restrict__ ob,
    int N, int K, int Kpart)
{
    __shared__ __align__(16) bf16 sA[2][64 * 32];
    __shared__ __align__(16) bf16 sB[2][64 * 32];

    const int l    = threadIdx.x;
    const int quad = l >> 4;
    const int l15  = l & 15;

    int bxs, bys, bzs;
    xcd_swizzle(bxs, bys, bzs);
    const int bm = bys * 64;
    const int bn = bxs * 64;
    const int kbase = bzs * Kpart;

    // per-lane staging geometry: 4 chunks (16B) per matrix, rows g*16 + (l>>2)
    int rS[4], cS[4];
#pragma unroll
    for (int g = 0; g < 4; g++) {
        rS[g] = g * 16 + (l >> 2);
        cS[g] = (((l & 3) ^ ((rS[g] >> 1) & 3)) * 8);
    }
    const bf16* Abase = A  + kbase;
    const bf16* Bbase = WT + kbase;

    const int nk = Kpart >> 5;

    auto stage = [&](int kt, int buf) {
#pragma unroll
        for (int g = 0; g < 4; g++)
            async16(Abase + (size_t)(bm + rS[g]) * K + kt * 32 + cS[g], sA[buf] + (g * 64 + l) * 8);
#pragma unroll
        for (int g = 0; g < 4; g++)
            async16(Bbase + (size_t)(bn + rS[g]) * K + kt * 32 + cS[g], sB[buf] + (g * 64 + l) * 8);
    };

    f32x4 acc[4][4];
#pragma unroll
    for (int i = 0; i < 4; i++)
#pragma unroll
        for (int j = 0; j < 4; j++)
#pragma unroll
            for (int r = 0; r < 4; r++) acc[i][j][r] = 0.0f;

    stage(0, 0);
    if (nk > 1) stage(1, 1);

    const int chF = (quad ^ ((l15 >> 1) & 3)) * 8;

    for (int kt = 0; kt < nk; kt++) {
        const int cur = kt & 1;
        if (kt + 1 < nk) { asm volatile("s_waitcnt vmcnt(8)" ::: "memory"); }
        else             { asm volatile("s_waitcnt vmcnt(0)" ::: "memory"); }
        __builtin_amdgcn_sched_barrier(0);
        bf16x8 af[4], bfr[4];
#pragma unroll
        for (int i = 0; i < 4; i++)
            af[i] = *(const bf16x8*)(sA[cur] + (i * 16 + l15) * 32 + chF);
#pragma unroll
        for (int i = 0; i < 4; i++)
            bfr[i] = *(const bf16x8*)(sB[cur] + (i * 16 + l15) * 32 + chF);
#pragma unroll
        for (int mt = 0; mt < 4; mt++)
#pragma unroll
            for (int nt = 0; nt < 4; nt++)
                acc[mt][nt] = MFMA16(af[mt], bfr[nt], acc[mt][nt]);
        __builtin_amdgcn_sched_barrier(0);
        if (kt + 2 < nk) stage(kt + 2, cur);   // WAR-safe: buf's ds_reads retired
    }

    float* po = (bzs == 0) ? o0 : (bzs == 1) ? o1 : o2;

#pragma unroll
    for (int nt = 0; nt < 4; nt++) {
        const int col = bn + nt * 16 + l15;
        float bias = 0.0f;
        if (MODE == 0)
            bias = (col < s1) ? b0[col] : (col < s2) ? b1[col - s1] : b2[col - s2];
#pragma unroll
        for (int mt = 0; mt < 4; mt++) {
#pragma unroll
            for (int r = 0; r < 4; r++) {
                const int row = bm + mt * 16 + quad * 4 + r;
                const float v = acc[mt][nt][r] + bias;
                if (MODE == 1) po[(size_t)row * N + col] = v;
                else           ob[(size_t)row * N + col] = (bf16)v;
            }
        }
    }
}

// ---------------------------------------------------------------------------
// 4-wave GEMM (r3 structure) — used for FF1 only (BM=128, gelu epilogue).
// ---------------------------------------------------------------------------
template <int MODE, int BM>
__global__ __launch_bounds__(256) void gemm_kernel(
    const bf16* __restrict__ A, const bf16* __restrict__ WT,
    const float* __restrict__ b0, const float* __restrict__ b1, const float* __restrict__ b2,
    int s1, int s2,
    void* __restrict__ o0, void* __restrict__ o1,
    int N, int K, int Kpart)
{
    constexpr int MT = BM / 32;
    __shared__ __align__(16) bf16 sA[2][BM * 32];
    __shared__ __align__(16) bf16 sB[2][128 * 32];

    const int tid  = threadIdx.x;
    const int lane = tid & 63;
    const int wave = tid >> 6;
    const int quad = lane >> 4;
    const int l15  = lane & 15;
    const int wm   = (wave >> 1) * (BM / 2);
    const int wn   = (wave & 1) * 64;

    int bxs, bys, bzs;
    xcd_swizzle(bxs, bys, bzs);
    const int bm = bys * BM;
    const int bn = bxs * 128;
    const int kbase = bzs * Kpart;

    f32x4 acc[MT][4];
#pragma unroll
    for (int i = 0; i < MT; i++)
#pragma unroll
        for (int j = 0; j < 4; j++)
#pragma unroll
            for (int r = 0; r < 4; r++) acc[i][j][r] = 0.0f;

    const int idx1 = tid + 256;
    const int ra0 = tid >> 2,  ca0 = (((tid  & 3) ^ ((ra0 >> 1) & 3)) * 8);
    const int rb1 = idx1 >> 2, cb1 = (((idx1 & 3) ^ ((rb1 >> 1) & 3)) * 8);

    const bf16* Arow0 = A + (size_t)(bm + ra0) * K + kbase + ca0;
    const bf16* Arow1 = (BM == 128) ? A + (size_t)(bm + rb1) * K + kbase + cb1 : A;
    const bf16* Brow0 = WT + (size_t)(bn + ra0) * K + kbase + ca0;
    const bf16* Brow1 = WT + (size_t)(bn + rb1) * K + kbase + cb1;

    const int nk = Kpart >> 5;

    async16(Arow0, sA[0] + tid * 8);
    if (BM == 128) async16(Arow1, sA[0] + idx1 * 8);
    async16(Brow0, sB[0] + tid * 8);
    async16(Brow1, sB[0] + idx1 * 8);

    const int chF = (quad ^ ((l15 >> 1) & 3)) * 8;

    int cur = 0;
    for (int kt = 0; kt < nk; kt++) {
        if (kt + 1 < nk) {
            const int ko = (kt + 1) * 32;
            async16(Arow0 + ko, sA[cur ^ 1] + tid * 8);
            if (BM == 128) async16(Arow1 + ko, sA[cur ^ 1] + idx1 * 8);
            async16(Brow0 + ko, sB[cur ^ 1] + tid * 8);
            async16(Brow1 + ko, sB[cur ^ 1] + idx1 * 8);
            if (BM == 128) SYNC_VM(4);
            else           SYNC_VM(3);
        } else {
            SYNC_VM(0);
        }
        bf16x8 af[MT], bfr[4];
#pragma unroll
        for (int i = 0; i < MT; i++)
            af[i] = *(const bf16x8*)(sA[cur] + (wm + i * 16 + l15) * 32 + chF);
#pragma unroll
        for (int i = 0; i < 4; i++)
            bfr[i] = *(const bf16x8*)(sB[cur] + (wn + i * 16 + l15) * 32 + chF);
#pragma unroll
        for (int mt = 0; mt < MT; mt++)
#pragma unroll
            for (int nt = 0; nt < 4; nt++)
                acc[mt][nt] = MFMA16(af[mt], bfr[nt], acc[mt][nt]);
        SYNC_LGKM();
        cur ^= 1;
    }

    void* outp = (bzs == 0) ? o0 : o1;

#pragma unroll
    for (int nt = 0; nt < 4; nt++) {
        const int col = bn + wn + nt * 16 + l15;
        float bias = 0.0f;
        if (MODE != 1)
            bias = (col < s1) ? b0[col] : (col < s2) ? b1[col - s1] : b2[col - s2];
#pragma unroll
        for (int mt = 0; mt < MT; mt++) {
#pragma unroll
            for (int r = 0; r < 4; r++) {
                const int row = bm + wm + mt * 16 + quad * 4 + r;
                float v = acc[mt][nt][r] + bias;
                if (MODE == 2) v = 0.5f * v * (1.0f + erff(v * 0.70710678118654752f));
                if (MODE == 1) ((float*)outp)[(size_t)row * N + col] = v;
                else           ((bf16*)outp)[(size_t)row * N + col] = (bf16)v;
            }
        }
    }
}

// ---------------------------------------------------------------------------
// V-transpose: qkv V-part [key][dim] -> vT[bh][dim][key].
// ---------------------------------------------------------------------------
__global__ __launch_bounds__(256) void vtrans_kernel(
    const bf16* __restrict__ qkv, bf16* __restrict__ vT)
{
    const int bh = blockIdx.y;
    const int b = bh / 12, h = bh - b * 12;
    const int k0 = blockIdx.x * 128;
    __shared__ __align__(16) bf16 tile[128 * 72];
    const int tid = threadIdx.x;
    const bf16* src = qkv + (size_t)(b * 512 + k0) * 2304 + 1536 + h * 64;
#pragma unroll
    for (int i = 0; i < 4; i++) {
        const int idx = i * 256 + tid;
        const int r = idx >> 3, c = (idx & 7) * 8;
        *(uint4*)(tile + r * 72 + c) = *(const uint4*)(src + (size_t)r * 2304 + c);
    }
    __syncthreads();
    bf16* dst = vT + (size_t)bh * 64 * 512 + k0;
#pragma unroll
    for (int i = 0; i < 4; i++) {
        const int idx = i * 256 + tid;
        const int d = idx & 63, kg = idx >> 6;
        alignas(16) bf16 tmp[8];
#pragma unroll
        for (int e = 0; e < 8; e++) tmp[e] = tile[(kg * 8 + e) * 72 + d];
        *(uint4*)(dst + (size_t)d * 512 + kg * 8) = *(uint4*)tmp;
    }
}

// ---------------------------------------------------------------------------
// Attention (r3 structure): counted-vmcnt K/V staging, XOR-swizzled tiles,
// Q in registers, V(0) stage hidden under softmax.
// ---------------------------------------------------------------------------
__global__ __launch_bounds__(256) void attn_kernel(
    const bf16* __restrict__ qkv, const bf16* __restrict__ vT,
    const float* __restrict__ mask, bf16* __restrict__ ctx)
{
    int bxs, bys, bzs;
    xcd_swizzle(bxs, bys, bzs);
    const int b = bzs, h = bys, q0 = bxs * 32;
    const int bh = b * 12 + h;
    const int tid = threadIdx.x, lane = tid & 63, wave = tid >> 6;
    const int quad = lane >> 4, l15 = lane & 15;
    const int mt = wave & 1;
    const int whi = wave >> 1;

    __shared__ __align__(16) bf16 sKV[2][64 * 64];
    __shared__ __align__(16) bf16 sS[32 * 520];
    __shared__ float sAM[512];
    __shared__ float sRed[256];
    __shared__ float sRow[32];

    for (int i = tid; i < 512; i += 256)
        sAM[i] = (1.0f - mask[b * 512 + i]) * -10000.0f;

    const size_t RS = 2304;
    const bf16* Qrow = qkv + (size_t)(b * 512 + q0 + mt * 16 + l15) * RS + h * 64;
    const bf16x8 aQ0 = *(const bf16x8*)(Qrow + quad * 8);
    const bf16x8 aQ1 = *(const bf16x8*)(Qrow + 32 + quad * 8);

    const int c0 = tid, c1 = tid + 256;
    const int r0 = c0 >> 3, r1 = c1 >> 3;
    const int sc0 = ((c0 & 7) ^ (r0 & 7)) * 8;
    const int sc1 = ((c1 & 7) ^ (r1 & 7)) * 8;

    const bf16* Kbase = qkv + (size_t)(b * 512) * RS + 768 + h * 64;

    async16(Kbase + (size_t)(r0) * RS + sc0, (bf16*)sKV[0] + c0 * 8);
    async16(Kbase + (size_t)(r1) * RS + sc1, (bf16*)sKV[0] + c1 * 8);

#pragma unroll
    for (int kt = 0; kt < 8; kt++) {
        const int cur = kt & 1;
        if (kt < 7) {
            async16(Kbase + (size_t)((kt + 1) * 64 + r0) * RS + sc0, (bf16*)sKV[cur ^ 1] + c0 * 8);
            async16(Kbase + (size_t)((kt + 1) * 64 + r1) * RS + sc1, (bf16*)sKV[cur ^ 1] + c1 * 8);
            SYNC_VM(2);
        } else {
            SYNC_VM(0);
        }
#pragma unroll
        for (int n = 0; n < 2; n++) {
            const int nt = whi * 2 + n;
            const int krow = nt * 16 + l15;
            const int sw = krow & 7;
            bf16x8 bK0 = *(const bf16x8*)(sKV[cur] + krow * 64 + ((quad ^ sw) * 8));
            bf16x8 bK1 = *(const bf16x8*)(sKV[cur] + krow * 64 + (((4 + quad) ^ sw) * 8));
            f32x4 accS;
#pragma unroll
            for (int r = 0; r < 4; r++) accS[r] = 0.0f;
            accS = MFMA16(aQ0, bK0, accS);
            accS = MFMA16(aQ1, bK1, accS);
#pragma unroll
            for (int r = 0; r < 4; r++) {
                const int row = mt * 16 + quad * 4 + r;
                sS[row * 520 + kt * 64 + nt * 16 + l15] = (bf16)accS[r];
            }
        }
        SYNC_LGKM();
    }

    const bf16* Vbase = vT + (size_t)bh * 64 * 512;
    async16(Vbase + (size_t)r0 * 512 + sc0, (bf16*)sKV[0] + c0 * 8);
    async16(Vbase + (size_t)r1 * 512 + sc1, (bf16*)sKV[0] + c1 * 8);

    {
        const int r = tid >> 3, p = tid & 7;
        float mx = -1e30f;
#pragma unroll
        for (int t = 0; t < 8; t++) {
            const int v0 = (p + 8 * t) * 8;
            bf16x8 pv = *(const bf16x8*)(sS + r * 520 + v0);
#pragma unroll
            for (int e = 0; e < 8; e++)
                mx = fmaxf(mx, (float)pv[e] * 0.125f + sAM[v0 + e]);
        }
        sRed[r * 8 + p] = mx;
        SYNC_LGKM();
#pragma unroll
        for (int q = 0; q < 8; q++) mx = fmaxf(mx, sRed[r * 8 + q]);
        float sum = 0.0f;
#pragma unroll
        for (int t = 0; t < 8; t++) {
            const int v0 = (p + 8 * t) * 8;
            bf16x8 pv = *(const bf16x8*)(sS + r * 520 + v0);
            bf16x8 ev;
#pragma unroll
            for (int e = 0; e < 8; e++) {
                const float x = __expf((float)pv[e] * 0.125f + sAM[v0 + e] - mx);
                sum += x;
                ev[e] = (bf16)x;
            }
            *(bf16x8*)(sS + r * 520 + v0) = ev;
        }
        SYNC_LGKM();
        sRed[r * 8 + p] = sum;
        SYNC_LGKM();
        if (p == 0) {
            float s = 0.0f;
#pragma unroll
            for (int q = 0; q < 8; q++) s += sRed[r * 8 + q];
            sRow[r] = s;
        }
    }

    f32x4 accO[2];
#pragma unroll
    for (int i = 0; i < 2; i++)
#pragma unroll
        for (int r = 0; r < 4; r++) accO[i][r] = 0.0f;

#pragma unroll
    for (int kt = 0; kt < 8; kt++) {
        const int cur = kt & 1;
        if (kt < 7) {
            async16(Vbase + (size_t)r0 * 512 + (kt + 1) * 64 + sc0, (bf16*)sKV[cur ^ 1] + c0 * 8);
            async16(Vbase + (size_t)r1 * 512 + (kt + 1) * 64 + sc1, (bf16*)sKV[cur ^ 1] + c1 * 8);
            SYNC_VM(2);
        } else {
            SYNC_VM(0);
        }
#pragma unroll
        for (int kk = 0; kk < 2; kk++) {
            bf16x8 aP = *(const bf16x8*)(sS + (mt * 16 + l15) * 520 + kt * 64 + kk * 32 + quad * 8);
#pragma unroll
            for (int n = 0; n < 2; n++) {
                const int vrow = whi * 32 + n * 16 + l15;
                bf16x8 bV = *(const bf16x8*)(sKV[cur] + vrow * 64 + (((kk * 4 + quad) ^ (vrow & 7)) * 8));
                accO[n] = MFMA16(aP, bV, accO[n]);
            }
        }
        SYNC_LGKM();
    }
#pragma unroll
    for (int n = 0; n < 2; n++) {
#pragma unroll
        for (int r = 0; r < 4; r++) {
            const int row = mt * 16 + quad * 4 + r;
            const float o = accO[n][r] / sRow[row];
            ctx[(size_t)(b * 512 + q0 + row) * 768 + h * 64 + whi * 32 + n * 16 + l15] = (bf16)o;
        }
    }
}

// ---------------------------------------------------------------------------
// Fused split-K reduce (up to 3 partials) + bias + residual-add + LayerNorm.
// NO __restrict__: p-inputs may exactly overlay out_f32 (same-index overlay;
// per-thread read-before-write, rows block-exclusive -> safe).
// ---------------------------------------------------------------------------
template <int NP>
__global__ __launch_bounds__(256) void ln_kernel(
    const float* p0, const float* p1, const float* p2,
    const float* bias, const float* resid,
    const float* g, const float* bb,
    bf16* out_bf, float* out_f32)
{
    const int row = blockIdx.x;
    const int tid = threadIdx.x;
    __shared__ float sS[4], sQ[4];

    float x[3], s = 0.0f, sq = 0.0f;
#pragma unroll
    for (int j = 0; j < 3; j++) {
        const int c = tid + j * 256;
        const size_t idx = (size_t)row * 768 + c;
        float v = p0[idx] + bias[c] + resid[idx];
        if (NP > 1) v += p1[idx];
        if (NP > 2) v += p2[idx];
        x[j] = v; s += v; sq += v * v;
    }
#pragma unroll
    for (int off = 32; off; off >>= 1) { s += __shfl_down(s, off); sq += __shfl_down(sq, off); }
    if ((tid & 63) == 0) { sS[tid >> 6] = s; sQ[tid >> 6] = sq; }
    __syncthreads();
    s  = sS[0] + sS[1] + sS[2] + sS[3];
    sq = sQ[0] + sQ[1] + sQ[2] + sQ[3];
    const float mean = s * (1.0f / 768.0f);
    float var = sq * (1.0f / 768.0f) - mean * mean;
    var = fmaxf(var, 0.0f);
    const float rstd = rsqrtf(var + 1e-12f);
#pragma unroll
    for (int j = 0; j < 3; j++) {
        const int c = tid + j * 256;
        const float v = (x[j] - mean) * rstd * g[c] + bb[c];
        out_bf[(size_t)row * 768 + c] = (bf16)v;
        out_f32[(size_t)row * 768 + c] = v;
    }
}

// ---------------------------------------------------------------------------
// Transpose + quantize all 6 fp32 weight matrices of one layer into bf16 wT.
// ---------------------------------------------------------------------------
__global__ __launch_bounds__(256) void transpose_kernel(
    const float* __restrict__ Wq, const float* __restrict__ Wk, const float* __restrict__ Wv,
    const float* __restrict__ Wao, const float* __restrict__ Wi, const float* __restrict__ Wo,
    bf16* __restrict__ wT)
{
    __shared__ bf16 tile[64 * 68];
    int id = blockIdx.x;
    const float* src; bf16* dst; int Kd, Nd;
    if (id < 576) {
        const int w = id / 144; id -= w * 144;
        Kd = 768; Nd = 768;
        src = (w == 0) ? Wq : (w == 1) ? Wk : (w == 2) ? Wv : Wao;
        dst = wT + (size_t)w * 589824;
    } else if (id < 1152) {
        id -= 576; Kd = 768; Nd = 3072; src = Wi; dst = wT + 2359296;
    } else {
        id -= 1152; Kd = 3072; Nd = 768; src = Wo; dst = wT + 4718592;
    }
    const int tn = Nd >> 6;
    const int tr = id / tn, tc = id - tr * tn;
    const int r0 = tr * 64, c0 = tc * 64;
    const int tid = threadIdx.x;

#pragma unroll
    for (int i = 0; i < 4; i++) {
        const int idx = i * 256 + tid;
        const int r = idx >> 4, c4 = (idx & 15) * 4;
        const float4 f = *(const float4*)(src + (size_t)(r0 + r) * Nd + c0 + c4);
        alignas(8) bf16 q[4] = {(bf16)f.x, (bf16)f.y, (bf16)f.z, (bf16)f.w};
        *(ushort4*)(tile + r * 68 + c4) = *(ushort4*)q;
    }
    __syncthreads();
#pragma unroll
    for (int i = 0; i < 4; i++) {
        const int idx = i * 256 + tid;
        const int n = idx >> 4, kc = (idx & 15) * 4;
        alignas(8) bf16 tmp[4];
#pragma unroll
        for (int e = 0; e < 4; e++) tmp[e] = tile[(kc + e) * 68 + n];
        *(ushort4*)(dst + (size_t)(c0 + n) * Kd + r0 + kc) = *(ushort4*)tmp;
    }
}

__global__ __launch_bounds__(256) void convert_kernel(
    const float* __restrict__ in, bf16* __restrict__ out, int n)
{
    const int i = blockIdx.x * 256 + threadIdx.x;
    if (i < n) out[i] = (bf16)in[i];
}

// ---------------------------------------------------------------------------
extern "C" void kernel_launch(void* const* d_in, const int* in_sizes, int n_in,
                              void* d_out, int out_size, void* d_ws, size_t ws_size,
                              hipStream_t stream)
{
    const float* hidden = (const float*)d_in[0];
    const float* mask   = (const float*)d_in[1];
    const float* Wq  = (const float*)d_in[2];  const float* bq  = (const float*)d_in[3];
    const float* Wk  = (const float*)d_in[4];  const float* bk  = (const float*)d_in[5];
    const float* Wv  = (const float*)d_in[6];  const float* bv  = (const float*)d_in[7];
    const float* Wao = (const float*)d_in[8];  const float* bao = (const float*)d_in[9];
    const float* g1  = (const float*)d_in[10]; const float* be1 = (const float*)d_in[11];
    const float* Wi  = (const float*)d_in[12]; const float* bi  = (const float*)d_in[13];
    const float* Wo  = (const float*)d_in[14]; const float* bo  = (const float*)d_in[15];
    const float* g2  = (const float*)d_in[16]; const float* be2 = (const float*)d_in[17];

    // workspace layout (95,944,704 B):
    //   wT    [0,          14155776)  bf16 weights (per layer)
    //   qkv   [14155776,   33030144)  bf16 4096x2304  (dead after attn)
    //   vT    [33030144,   39321600)  bf16            (dead after attn)
    //   ctx   [39321600,   45613056)  bf16            (dead after AO)
    //   attnb [45613056,   51904512)  bf16            (dead after FF1)
    //   xb    [51904512,   58195968)  bf16            (dead after QKV)
    //   xf    [58195968,   70778880)  f32 resid1      (dead after ln1)
    //   attnf [70778880,   83361792)  f32 resid2      (dead after ln2)
    //   spare [83361792,   95944704)  f32 12.58MB
    // partial aliases (each 12,582,912 B, lifetime-checked):
    //   AO  (runs after attn, before ln1):  pA0=qkv, pA1=qkv+12.58M (ends 39321600),
    //       pA2=spare.  ln1 reads pA*, resid=xf/hidden; writes attnb+attnf. OK.
    //   FF1 out ffh = [14155776, 39321600) (clobbers pA0/pA1 after ln1). OK.
    //   FF2 (after FF1, before ln2): pF0=ctx+attnb [39321600,51904512),
    //       pF1=xf [58195968,70778880), pF2=spare.  ln2 reads pF*+attnf,
    //       writes xb + (xf | d_out).  out_f32==pF1 at l<11: same-index overlay,
    //       per-thread read-before-write, rows block-exclusive -> safe (no restrict).
    char* ws = (char*)d_ws;
    bf16*  wT    = (bf16*)(ws);
    bf16*  qkv   = (bf16*)(ws + 14155776);
    bf16*  vT    = (bf16*)(ws + 33030144);
    bf16*  ctx   = (bf16*)(ws + 39321600);
    bf16*  attnb = (bf16*)(ws + 45613056);
    bf16*  xb    = (bf16*)(ws + 51904512);
    float* xf    = (float*)(ws + 58195968);
    float* attnf = (float*)(ws + 70778880);
    bf16*  ffh   = (bf16*)(ws + 14155776);
    float* pA0   = (float*)(ws + 14155776);
    float* pA1   = (float*)(ws + 26738688);
    float* pA2   = (float*)(ws + 83361792);
    float* pF0   = (float*)(ws + 39321600);
    float* pF1   = (float*)(ws + 58195968);
    float* pF2   = (float*)(ws + 83361792);

    convert_kernel<<<12288, 256, 0, stream>>>(hidden, xb, 3145728);

    for (int l = 0; l < 12; l++) {
        transpose_kernel<<<1728, 256, 0, stream>>>(
            Wq + (size_t)l * 589824, Wk + (size_t)l * 589824, Wv + (size_t)l * 589824,
            Wao + (size_t)l * 589824, Wi + (size_t)l * 2359296, Wo + (size_t)l * 2359296, wT);

        // QKV: M=4096 N=2304 K=768, 1-wave 64x64 -> 36x64 = 2304 blocks
        gemm1w_kernel<0><<<dim3(36, 64, 1), 64, 0, stream>>>(
            xb, wT, bq + l * 768, bk + l * 768, bv + l * 768, 768, 1536,
            nullptr, nullptr, nullptr, qkv, 2304, 768, 768);

        vtrans_kernel<<<dim3(4, 96), 256, 0, stream>>>(qkv, vT);

        attn_kernel<<<dim3(16, 12, 8), 256, 0, stream>>>(qkv, vT, mask, ctx);

        // AO: M=4096 N=768 K=768, 1-wave split-3 -> 12x64x3 = 2304 blocks
        gemm1w_kernel<1><<<dim3(12, 64, 3), 64, 0, stream>>>(
            ctx, wT + 1769472, nullptr, nullptr, nullptr, 0, 0,
            pA0, pA1, pA2, nullptr, 768, 768, 256);

        const float* resid1 = (l == 0) ? hidden : xf;
        ln_kernel<3><<<4096, 256, 0, stream>>>(
            pA0, pA1, pA2, bao + l * 768, resid1, g1 + l * 768, be1 + l * 768, attnb, attnf);

        // FF1: M=4096 N=3072 K=768, 4-wave BM=128 -> 768 blocks (control arm)
        gemm_kernel<2, 128><<<dim3(24, 32, 1), 256, 0, stream>>>(
            attnb, wT + 2359296, bi + l * 3072, bi + l * 3072, bi + l * 3072, 3072, 3072,
            ffh, nullptr, 3072, 768, 768);

        // FF2: M=4096 N=768 K=3072, 1-wave split-3 -> 12x64x3 = 2304 blocks
        gemm1w_kernel<1><<<dim3(12, 64, 3), 64, 0, stream>>>(
            ffh, wT + 4718592, nullptr, nullptr, nullptr, 0, 0,
            pF0, pF1, pF2, nullptr, 768, 3072, 1024);

        float* f32dst = (l == 11) ? (float*)d_out : xf;
        ln_kernel<3><<<4096, 256, 0, stream>>>(
            pF0, pF1, pF2, bo + l * 768, attnf, g2 + l * 768, be2 + l * 768, xb, f32dst);
    }
}

// Round 5
// 2550.282 us; speedup vs baseline: 1.0974x; 1.0974x over previous
//
#include <hip/hip_runtime.h>
#include <hip/hip_bf16.h>

typedef __bf16 bf16;
typedef __attribute__((ext_vector_type(8))) __bf16 bf16x8;
typedef __attribute__((ext_vector_type(4))) float f32x4;

#define MFMA16(a, b, c) __builtin_amdgcn_mfma_f32_16x16x32_bf16((a), (b), (c), 0, 0, 0)

#define WAIT_VM(N) asm volatile("s_waitcnt vmcnt(" #N ")" ::: "memory")
#define BAR() do { __builtin_amdgcn_s_barrier(); __builtin_amdgcn_sched_barrier(0); } while (0)
#define SYNC_VM(N) do { WAIT_VM(N); BAR(); } while (0)
#define SYNC_LGKM() do { asm volatile("s_waitcnt lgkmcnt(0)" ::: "memory"); BAR(); } while (0)

__device__ __forceinline__ void async16(const bf16* g, bf16* l) {
    __builtin_amdgcn_global_load_lds((__attribute__((address_space(1))) void*)(g),
                                     (__attribute__((address_space(3))) void*)(l), 16, 0, 0);
}

// Bijective XCD-chunked swizzle (m204).
__device__ __forceinline__ void xcd_swizzle(int& bx, int& by, int& bz) {
    const int gx = gridDim.x, gy = gridDim.y;
    const int nwg = gx * gy * gridDim.z;
    const int lin = blockIdx.x + gx * (blockIdx.y + gy * blockIdx.z);
    const int xcd = lin & 7, seq = lin >> 3;
    const int q = nwg >> 3, r = nwg & 7;
    const int nl = (xcd < r ? xcd * (q + 1) : r * (q + 1) + (xcd - r) * q) + seq;
    bx = nl % gx;
    const int t = nl / gx;
    by = t % gy;
    bz = t / gy;
}

// ---------------------------------------------------------------------------
// GEMM: C[M,N] = A[M,K-slice] @ WT[N,K-slice]^T (+ bias for MODE 0/2).
// MODE 0: bf16 out (+bias); MODE 1: f32 partial out, NO bias; MODE 2: gelu+bias.
// BM in {64,128}, BN=128, BK=32; 256 thr = 4 waves 2x2.
// DEPTH-2 prefetch, triple-buffered LDS: tiles kt, kt+1, kt+2 in flight;
// the per-iter wait releases as soon as tile kt lands while kt+1/kt+2 stay
// in flight (T4 counted-vmcnt: N = loads/tile x tiles-in-flight-past-wait).
//   per-thread loads/tile LPT = 4 (BM=128) or 3 (BM=64)
//   steady wait: vmcnt(2*LPT); tail: vmcnt(LPT); last: vmcnt(0)
// WAR: stage(kt+3) overwrites buf[kt%3] only after SYNC_LGKM proves all
// waves' ds_reads from it retired.
// T2 chunk-XOR swizzle (verified r3): src col-chunk ^= (row>>1)&3,
// fragment read chunk = quad ^ ((l15>>1)&3).
// ---------------------------------------------------------------------------
template <int MODE, int BM>
__global__ __launch_bounds__(256) void gemm_kernel(
    const bf16* __restrict__ A, const bf16* __restrict__ WT,
    const float* __restrict__ b0, const float* __restrict__ b1, const float* __restrict__ b2,
    int s1, int s2,
    void* __restrict__ o0, void* __restrict__ o1,
    int N, int K, int Kpart)
{
    constexpr int MT = BM / 32;
    __shared__ __align__(16) bf16 sA[3][BM * 32];
    __shared__ __align__(16) bf16 sB[3][128 * 32];

    const int tid  = threadIdx.x;
    const int lane = tid & 63;
    const int wave = tid >> 6;
    const int quad = lane >> 4;
    const int l15  = lane & 15;
    const int wm   = (wave >> 1) * (BM / 2);
    const int wn   = (wave & 1) * 64;

    int bxs, bys, bzs;
    xcd_swizzle(bxs, bys, bzs);
    const int bm = bys * BM;
    const int bn = bxs * 128;
    const int kbase = bzs * Kpart;

    f32x4 acc[MT][4];
#pragma unroll
    for (int i = 0; i < MT; i++)
#pragma unroll
        for (int j = 0; j < 4; j++)
#pragma unroll
            for (int r = 0; r < 4; r++) acc[i][j][r] = 0.0f;

    const int idx1 = tid + 256;
    const int ra0 = tid >> 2,  ca0 = (((tid  & 3) ^ ((ra0 >> 1) & 3)) * 8);
    const int rb1 = idx1 >> 2, cb1 = (((idx1 & 3) ^ ((rb1 >> 1) & 3)) * 8);

    const bf16* Arow0 = A + (size_t)(bm + ra0) * K + kbase + ca0;
    const bf16* Arow1 = (BM == 128) ? A + (size_t)(bm + rb1) * K + kbase + cb1 : A;
    const bf16* Brow0 = WT + (size_t)(bn + ra0) * K + kbase + ca0;
    const bf16* Brow1 = WT + (size_t)(bn + rb1) * K + kbase + cb1;

    const int nk = Kpart >> 5;

    auto stage = [&](int kt, int buf) {
        const int ko = kt * 32;
        async16(Arow0 + ko, sA[buf] + tid * 8);
        if (BM == 128) async16(Arow1 + ko, sA[buf] + idx1 * 8);
        async16(Brow0 + ko, sB[buf] + tid * 8);
        async16(Brow1 + ko, sB[buf] + idx1 * 8);
    };

    // prologue: fill the 3-deep pipeline
    stage(0, 0);
    if (nk > 1) stage(1, 1);
    if (nk > 2) stage(2, 2);

    const int chF = (quad ^ ((l15 >> 1) & 3)) * 8;

    int cur = 0;
    for (int kt = 0; kt < nk; kt++) {
        // wait for tile kt only; kt+1, kt+2 remain in flight
        if (kt + 2 < nk) {
            if (BM == 128) { WAIT_VM(8); } else { WAIT_VM(6); }
        } else if (kt + 1 < nk) {
            if (BM == 128) { WAIT_VM(4); } else { WAIT_VM(3); }
        } else {
            WAIT_VM(0);
        }
        BAR();

        bf16x8 af[MT], bfr[4];
#pragma unroll
        for (int i = 0; i < MT; i++)
            af[i] = *(const bf16x8*)(sA[cur] + (wm + i * 16 + l15) * 32 + chF);
#pragma unroll
        for (int i = 0; i < 4; i++)
            bfr[i] = *(const bf16x8*)(sB[cur] + (wn + i * 16 + l15) * 32 + chF);
#pragma unroll
        for (int mt = 0; mt < MT; mt++)
#pragma unroll
            for (int nt = 0; nt < 4; nt++)
                acc[mt][nt] = MFMA16(af[mt], bfr[nt], acc[mt][nt]);

        SYNC_LGKM();   // all waves' frag reads from buf[cur] retired
        if (kt + 3 < nk) stage(kt + 3, cur);   // reuse the buffer just drained
        cur = (cur == 2) ? 0 : cur + 1;
    }

    void* outp = (bzs == 0) ? o0 : o1;

#pragma unroll
    for (int nt = 0; nt < 4; nt++) {
        const int col = bn + wn + nt * 16 + l15;
        float bias = 0.0f;
        if (MODE != 1)
            bias = (col < s1) ? b0[col] : (col < s2) ? b1[col - s1] : b2[col - s2];
#pragma unroll
        for (int mt = 0; mt < MT; mt++) {
#pragma unroll
            for (int r = 0; r < 4; r++) {
                const int row = bm + wm + mt * 16 + quad * 4 + r;
                float v = acc[mt][nt][r] + bias;
                if (MODE == 2) v = 0.5f * v * (1.0f + erff(v * 0.70710678118654752f));
                if (MODE == 1) ((float*)outp)[(size_t)row * N + col] = v;
                else           ((bf16*)outp)[(size_t)row * N + col] = (bf16)v;
            }
        }
    }
}

// ---------------------------------------------------------------------------
// V-transpose: qkv V-part [key][dim] -> vT[bh][dim][key].
// ---------------------------------------------------------------------------
__global__ __launch_bounds__(256) void vtrans_kernel(
    const bf16* __restrict__ qkv, bf16* __restrict__ vT)
{
    const int bh = blockIdx.y;
    const int b = bh / 12, h = bh - b * 12;
    const int k0 = blockIdx.x * 128;
    __shared__ __align__(16) bf16 tile[128 * 72];
    const int tid = threadIdx.x;
    const bf16* src = qkv + (size_t)(b * 512 + k0) * 2304 + 1536 + h * 64;
#pragma unroll
    for (int i = 0; i < 4; i++) {
        const int idx = i * 256 + tid;
        const int r = idx >> 3, c = (idx & 7) * 8;
        *(uint4*)(tile + r * 72 + c) = *(const uint4*)(src + (size_t)r * 2304 + c);
    }
    __syncthreads();
    bf16* dst = vT + (size_t)bh * 64 * 512 + k0;
#pragma unroll
    for (int i = 0; i < 4; i++) {
        const int idx = i * 256 + tid;
        const int d = idx & 63, kg = idx >> 6;
        alignas(16) bf16 tmp[8];
#pragma unroll
        for (int e = 0; e < 8; e++) tmp[e] = tile[(kg * 8 + e) * 72 + d];
        *(uint4*)(dst + (size_t)d * 512 + kg * 8) = *(uint4*)tmp;
    }
}

// ---------------------------------------------------------------------------
// Attention (r3 structure, unchanged): counted-vmcnt K/V staging, XOR-swizzled
// tiles, Q in registers, V(0) stage hidden under softmax.
// ---------------------------------------------------------------------------
__global__ __launch_bounds__(256) void attn_kernel(
    const bf16* __restrict__ qkv, const bf16* __restrict__ vT,
    const float* __restrict__ mask, bf16* __restrict__ ctx)
{
    int bxs, bys, bzs;
    xcd_swizzle(bxs, bys, bzs);
    const int b = bzs, h = bys, q0 = bxs * 32;
    const int bh = b * 12 + h;
    const int tid = threadIdx.x, lane = tid & 63, wave = tid >> 6;
    const int quad = lane >> 4, l15 = lane & 15;
    const int mt = wave & 1;
    const int whi = wave >> 1;

    __shared__ __align__(16) bf16 sKV[2][64 * 64];
    __shared__ __align__(16) bf16 sS[32 * 520];
    __shared__ float sAM[512];
    __shared__ float sRed[256];
    __shared__ float sRow[32];

    for (int i = tid; i < 512; i += 256)
        sAM[i] = (1.0f - mask[b * 512 + i]) * -10000.0f;

    const size_t RS = 2304;
    const bf16* Qrow = qkv + (size_t)(b * 512 + q0 + mt * 16 + l15) * RS + h * 64;
    const bf16x8 aQ0 = *(const bf16x8*)(Qrow + quad * 8);
    const bf16x8 aQ1 = *(const bf16x8*)(Qrow + 32 + quad * 8);

    const int c0 = tid, c1 = tid + 256;
    const int r0 = c0 >> 3, r1 = c1 >> 3;
    const int sc0 = ((c0 & 7) ^ (r0 & 7)) * 8;
    const int sc1 = ((c1 & 7) ^ (r1 & 7)) * 8;

    const bf16* Kbase = qkv + (size_t)(b * 512) * RS + 768 + h * 64;

    async16(Kbase + (size_t)(r0) * RS + sc0, (bf16*)sKV[0] + c0 * 8);
    async16(Kbase + (size_t)(r1) * RS + sc1, (bf16*)sKV[0] + c1 * 8);

#pragma unroll
    for (int kt = 0; kt < 8; kt++) {
        const int cur = kt & 1;
        if (kt < 7) {
            async16(Kbase + (size_t)((kt + 1) * 64 + r0) * RS + sc0, (bf16*)sKV[cur ^ 1] + c0 * 8);
            async16(Kbase + (size_t)((kt + 1) * 64 + r1) * RS + sc1, (bf16*)sKV[cur ^ 1] + c1 * 8);
            SYNC_VM(2);
        } else {
            SYNC_VM(0);
        }
#pragma unroll
        for (int n = 0; n < 2; n++) {
            const int nt = whi * 2 + n;
            const int krow = nt * 16 + l15;
            const int sw = krow & 7;
            bf16x8 bK0 = *(const bf16x8*)(sKV[cur] + krow * 64 + ((quad ^ sw) * 8));
            bf16x8 bK1 = *(const bf16x8*)(sKV[cur] + krow * 64 + (((4 + quad) ^ sw) * 8));
            f32x4 accS;
#pragma unroll
            for (int r = 0; r < 4; r++) accS[r] = 0.0f;
            accS = MFMA16(aQ0, bK0, accS);
            accS = MFMA16(aQ1, bK1, accS);
#pragma unroll
            for (int r = 0; r < 4; r++) {
                const int row = mt * 16 + quad * 4 + r;
                sS[row * 520 + kt * 64 + nt * 16 + l15] = (bf16)accS[r];
            }
        }
        SYNC_LGKM();
    }

    const bf16* Vbase = vT + (size_t)bh * 64 * 512;
    async16(Vbase + (size_t)r0 * 512 + sc0, (bf16*)sKV[0] + c0 * 8);
    async16(Vbase + (size_t)r1 * 512 + sc1, (bf16*)sKV[0] + c1 * 8);

    {
        const int r = tid >> 3, p = tid & 7;
        float mx = -1e30f;
#pragma unroll
        for (int t = 0; t < 8; t++) {
            const int v0 = (p + 8 * t) * 8;
            bf16x8 pv = *(const bf16x8*)(sS + r * 520 + v0);
#pragma unroll
            for (int e = 0; e < 8; e++)
                mx = fmaxf(mx, (float)pv[e] * 0.125f + sAM[v0 + e]);
        }
        sRed[r * 8 + p] = mx;
        SYNC_LGKM();
#pragma unroll
        for (int q = 0; q < 8; q++) mx = fmaxf(mx, sRed[r * 8 + q]);
        float sum = 0.0f;
#pragma unroll
        for (int t = 0; t < 8; t++) {
            const int v0 = (p + 8 * t) * 8;
            bf16x8 pv = *(const bf16x8*)(sS + r * 520 + v0);
            bf16x8 ev;
#pragma unroll
            for (int e = 0; e < 8; e++) {
                const float x = __expf((float)pv[e] * 0.125f + sAM[v0 + e] - mx);
                sum += x;
                ev[e] = (bf16)x;
            }
            *(bf16x8*)(sS + r * 520 + v0) = ev;
        }
        SYNC_LGKM();
        sRed[r * 8 + p] = sum;
        SYNC_LGKM();
        if (p == 0) {
            float s = 0.0f;
#pragma unroll
            for (int q = 0; q < 8; q++) s += sRed[r * 8 + q];
            sRow[r] = s;
        }
    }

    f32x4 accO[2];
#pragma unroll
    for (int i = 0; i < 2; i++)
#pragma unroll
        for (int r = 0; r < 4; r++) accO[i][r] = 0.0f;

#pragma unroll
    for (int kt = 0; kt < 8; kt++) {
        const int cur = kt & 1;
        if (kt < 7) {
            async16(Vbase + (size_t)r0 * 512 + (kt + 1) * 64 + sc0, (bf16*)sKV[cur ^ 1] + c0 * 8);
            async16(Vbase + (size_t)r1 * 512 + (kt + 1) * 64 + sc1, (bf16*)sKV[cur ^ 1] + c1 * 8);
            SYNC_VM(2);
        } else {
            SYNC_VM(0);
        }
#pragma unroll
        for (int kk = 0; kk < 2; kk++) {
            bf16x8 aP = *(const bf16x8*)(sS + (mt * 16 + l15) * 520 + kt * 64 + kk * 32 + quad * 8);
#pragma unroll
            for (int n = 0; n < 2; n++) {
                const int vrow = whi * 32 + n * 16 + l15;
                bf16x8 bV = *(const bf16x8*)(sKV[cur] + vrow * 64 + (((kk * 4 + quad) ^ (vrow & 7)) * 8));
                accO[n] = MFMA16(aP, bV, accO[n]);
            }
        }
        SYNC_LGKM();
    }
#pragma unroll
    for (int n = 0; n < 2; n++) {
#pragma unroll
        for (int r = 0; r < 4; r++) {
            const int row = mt * 16 + quad * 4 + r;
            const float o = accO[n][r] / sRow[row];
            ctx[(size_t)(b * 512 + q0 + row) * 768 + h * 64 + whi * 32 + n * 16 + l15] = (bf16)o;
        }
    }
}

// ---------------------------------------------------------------------------
// Fused split-K reduce + bias + residual-add + LayerNorm.
// ---------------------------------------------------------------------------
template <int NP>
__global__ __launch_bounds__(256) void ln_kernel(
    const float* __restrict__ p0, const float* __restrict__ p1,
    const float* __restrict__ bias, const float* __restrict__ resid,
    const float* __restrict__ g, const float* __restrict__ bb,
    bf16* __restrict__ out_bf, float* __restrict__ out_f32)
{
    const int row = blockIdx.x;
    const int tid = threadIdx.x;
    __shared__ float sS[4], sQ[4];

    float x[3], s = 0.0f, sq = 0.0f;
#pragma unroll
    for (int j = 0; j < 3; j++) {
        const int c = tid + j * 256;
        const size_t idx = (size_t)row * 768 + c;
        float v = p0[idx] + bias[c] + resid[idx];
        if (NP > 1) v += p1[idx];
        x[j] = v; s += v; sq += v * v;
    }
#pragma unroll
    for (int off = 32; off; off >>= 1) { s += __shfl_down(s, off); sq += __shfl_down(sq, off); }
    if ((tid & 63) == 0) { sS[tid >> 6] = s; sQ[tid >> 6] = sq; }
    __syncthreads();
    s  = sS[0] + sS[1] + sS[2] + sS[3];
    sq = sQ[0] + sQ[1] + sQ[2] + sQ[3];
    const float mean = s * (1.0f / 768.0f);
    float var = sq * (1.0f / 768.0f) - mean * mean;
    var = fmaxf(var, 0.0f);
    const float rstd = rsqrtf(var + 1e-12f);
#pragma unroll
    for (int j = 0; j < 3; j++) {
        const int c = tid + j * 256;
        const float v = (x[j] - mean) * rstd * g[c] + bb[c];
        out_bf[(size_t)row * 768 + c] = (bf16)v;
        out_f32[(size_t)row * 768 + c] = v;
    }
}

// ---------------------------------------------------------------------------
// Transpose + quantize all 6 fp32 weight matrices of one layer into bf16 wT.
// ---------------------------------------------------------------------------
__global__ __launch_bounds__(256) void transpose_kernel(
    const float* __restrict__ Wq, const float* __restrict__ Wk, const float* __restrict__ Wv,
    const float* __restrict__ Wao, const float* __restrict__ Wi, const float* __restrict__ Wo,
    bf16* __restrict__ wT)
{
    __shared__ bf16 tile[64 * 68];
    int id = blockIdx.x;
    const float* src; bf16* dst; int Kd, Nd;
    if (id < 576) {
        const int w = id / 144; id -= w * 144;
        Kd = 768; Nd = 768;
        src = (w == 0) ? Wq : (w == 1) ? Wk : (w == 2) ? Wv : Wao;
        dst = wT + (size_t)w * 589824;
    } else if (id < 1152) {
        id -= 576; Kd = 768; Nd = 3072; src = Wi; dst = wT + 2359296;
    } else {
        id -= 1152; Kd = 3072; Nd = 768; src = Wo; dst = wT + 4718592;
    }
    const int tn = Nd >> 6;
    const int tr = id / tn, tc = id - tr * tn;
    const int r0 = tr * 64, c0 = tc * 64;
    const int tid = threadIdx.x;

#pragma unroll
    for (int i = 0; i < 4; i++) {
        const int idx = i * 256 + tid;
        const int r = idx >> 4, c4 = (idx & 15) * 4;
        const float4 f = *(const float4*)(src + (size_t)(r0 + r) * Nd + c0 + c4);
        alignas(8) bf16 q[4] = {(bf16)f.x, (bf16)f.y, (bf16)f.z, (bf16)f.w};
        *(ushort4*)(tile + r * 68 + c4) = *(ushort4*)q;
    }
    __syncthreads();
#pragma unroll
    for (int i = 0; i < 4; i++) {
        const int idx = i * 256 + tid;
        const int n = idx >> 4, kc = (idx & 15) * 4;
        alignas(8) bf16 tmp[4];
#pragma unroll
        for (int e = 0; e < 4; e++) tmp[e] = tile[(kc + e) * 68 + n];
        *(ushort4*)(dst + (size_t)(c0 + n) * Kd + r0 + kc) = *(ushort4*)tmp;
    }
}

__global__ __launch_bounds__(256) void convert_kernel(
    const float* __restrict__ in, bf16* __restrict__ out, int n)
{
    const int i = blockIdx.x * 256 + threadIdx.x;
    if (i < n) out[i] = (bf16)in[i];
}

// ---------------------------------------------------------------------------
extern "C" void kernel_launch(void* const* d_in, const int* in_sizes, int n_in,
                              void* d_out, int out_size, void* d_ws, size_t ws_size,
                              hipStream_t stream)
{
    const float* hidden = (const float*)d_in[0];
    const float* mask   = (const float*)d_in[1];
    const float* Wq  = (const float*)d_in[2];  const float* bq  = (const float*)d_in[3];
    const float* Wk  = (const float*)d_in[4];  const float* bk  = (const float*)d_in[5];
    const float* Wv  = (const float*)d_in[6];  const float* bv  = (const float*)d_in[7];
    const float* Wao = (const float*)d_in[8];  const float* bao = (const float*)d_in[9];
    const float* g1  = (const float*)d_in[10]; const float* be1 = (const float*)d_in[11];
    const float* Wi  = (const float*)d_in[12]; const float* bi  = (const float*)d_in[13];
    const float* Wo  = (const float*)d_in[14]; const float* bo  = (const float*)d_in[15];
    const float* g2  = (const float*)d_in[16]; const float* be2 = (const float*)d_in[17];

    // workspace layout (95,944,704 B) — identical to r3 (lifetime-checked):
    //   wT    [0,          14155776)  bf16 weights (per layer)
    //   qkv   [14155776,   33030144)  bf16 4096x2304  (dead after attn)
    //   vT    [33030144,   39321600)  bf16            (dead after attn)
    //   ctx   [39321600,   45613056)  bf16            (dead after AO)
    //   attnb [45613056,   51904512)  bf16            (dead after FF1)
    //   xb    [51904512,   58195968)  bf16            (dead after QKV)
    //   xf    [58195968,   70778880)  f32 resid1      (dead after ln1)
    //   attnf [70778880,   83361792)  f32 resid2      (dead after ln2)
    //   spare [83361792,   95944704)  f32 12.58MB
    // partial aliases:
    //   AO (after attn, before ln1): pA0=qkv base, pA1=qkv+12.58MB
    //       (both inside [14155776,39321600), dead after attn). OK.
    //   ffh = [14155776, 39321600) FF1 out (clobbers pA* after ln1). OK.
    //   FF2: pF0=[39321600,51904512) (ctx+attnb, dead), pF1=spare. OK.
    char* ws = (char*)d_ws;
    bf16*  wT    = (bf16*)(ws);
    bf16*  qkv   = (bf16*)(ws + 14155776);
    bf16*  vT    = (bf16*)(ws + 33030144);
    bf16*  ctx   = (bf16*)(ws + 39321600);
    bf16*  attnb = (bf16*)(ws + 45613056);
    bf16*  xb    = (bf16*)(ws + 51904512);
    float* xf    = (float*)(ws + 58195968);
    float* attnf = (float*)(ws + 70778880);
    bf16*  ffh   = (bf16*)(ws + 14155776);
    float* pA0   = (float*)(ws + 14155776);
    float* pA1   = (float*)(ws + 26738688);
    float* pF0   = (float*)(ws + 39321600);
    float* pF1   = (float*)(ws + 83361792);

    convert_kernel<<<12288, 256, 0, stream>>>(hidden, xb, 3145728);

    for (int l = 0; l < 12; l++) {
        transpose_kernel<<<1728, 256, 0, stream>>>(
            Wq + (size_t)l * 589824, Wk + (size_t)l * 589824, Wv + (size_t)l * 589824,
            Wao + (size_t)l * 589824, Wi + (size_t)l * 2359296, Wo + (size_t)l * 2359296, wT);

        // QKV: M=4096 N=2304 K=768, BM=64 -> 1152 blocks, nk=24
        gemm_kernel<0, 64><<<dim3(18, 64, 1), 256, 0, stream>>>(
            xb, wT, bq + l * 768, bk + l * 768, bv + l * 768, 768, 1536,
            qkv, nullptr, 2304, 768, 768);

        vtrans_kernel<<<dim3(4, 96), 256, 0, stream>>>(qkv, vT);

        attn_kernel<<<dim3(16, 12, 8), 256, 0, stream>>>(qkv, vT, mask, ctx);

        // AO: M=4096 N=768 K=768, BM=64 split-2 -> 768 blocks, nk=12
        gemm_kernel<1, 64><<<dim3(6, 64, 2), 256, 0, stream>>>(
            ctx, wT + 1769472, nullptr, nullptr, nullptr, 0, 0,
            pA0, pA1, 768, 768, 384);

        const float* resid1 = (l == 0) ? hidden : xf;
        ln_kernel<2><<<4096, 256, 0, stream>>>(
            pA0, pA1, bao + l * 768, resid1, g1 + l * 768, be1 + l * 768, attnb, attnf);

        // FF1: M=4096 N=3072 K=768, BM=128 -> 768 blocks, nk=24
        gemm_kernel<2, 128><<<dim3(24, 32, 1), 256, 0, stream>>>(
            attnb, wT + 2359296, bi + l * 3072, bi + l * 3072, bi + l * 3072, 3072, 3072,
            ffh, nullptr, 3072, 768, 768);

        // FF2: M=4096 N=768 K=3072, BM=64 split-2 -> 768 blocks, nk=48
        gemm_kernel<1, 64><<<dim3(6, 64, 2), 256, 0, stream>>>(
            ffh, wT + 4718592, nullptr, nullptr, nullptr, 0, 0,
            pF0, pF1, 768, 3072, 1536);

        float* f32dst = (l == 11) ? (float*)d_out : xf;
        ln_kernel<2><<<4096, 256, 0, stream>>>(
            pF0, pF1, bo + l * 768, attnf, g2 + l * 768, be2 + l * 768, xb, f32dst);
    }
}

// Round 6
// 2547.582 us; speedup vs baseline: 1.0986x; 1.0011x over previous
//
#include <hip/hip_runtime.h>
#include <hip/hip_bf16.h>

typedef __bf16 bf16;
typedef __attribute__((ext_vector_type(8))) __bf16 bf16x8;
typedef __attribute__((ext_vector_type(4))) float f32x4;

#define MFMA16(a, b, c) __builtin_amdgcn_mfma_f32_16x16x32_bf16((a), (b), (c), 0, 0, 0)

#define WAIT_VM(N) asm volatile("s_waitcnt vmcnt(" #N ")" ::: "memory")
#define BAR() do { __builtin_amdgcn_s_barrier(); __builtin_amdgcn_sched_barrier(0); } while (0)
#define SYNC_VM(N) do { WAIT_VM(N); BAR(); } while (0)
#define SYNC_LGKM() do { asm volatile("s_waitcnt lgkmcnt(0)" ::: "memory"); BAR(); } while (0)

__device__ __forceinline__ void async16(const bf16* g, bf16* l) {
    __builtin_amdgcn_global_load_lds((__attribute__((address_space(1))) void*)(g),
                                     (__attribute__((address_space(3))) void*)(l), 16, 0, 0);
}

// Bijective XCD-chunked swizzle (m204).
__device__ __forceinline__ void xcd_swizzle(int& bx, int& by, int& bz) {
    const int gx = gridDim.x, gy = gridDim.y;
    const int nwg = gx * gy * gridDim.z;
    const int lin = blockIdx.x + gx * (blockIdx.y + gy * blockIdx.z);
    const int xcd = lin & 7, seq = lin >> 3;
    const int q = nwg >> 3, r = nwg & 7;
    const int nl = (xcd < r ? xcd * (q + 1) : r * (q + 1) + (xcd - r) * q) + seq;
    bx = nl % gx;
    const int t = nl / gx;
    by = t % gy;
    bz = t / gy;
}

// ---------------------------------------------------------------------------
// GEMM: C[M,N] = A[M,K-slice] @ WT[N,K-slice]^T (+ bias for MODE 0/2).
// MODE 0: bf16 out (+bias); MODE 1: f32 partial out, NO bias; MODE 2: gelu+bias.
// BM=128, BN=256, BK=32; 512 thr = 8 waves in 2x4 (wave>>2 = row half,
// wave&3 = col quarter); each wave owns a 64x64 sub-tile (4x4 frags) —
// identical per-wave shape/swizzle/sync to the r3-verified kernel.
// WHY BN=256: staging traffic = M/BM*(N*K) + N/BN*(M*K); all rounds measured
// the staging path saturating at ~3.5-4 TB/s (r0 FF2 300MB/75us, r4 FF1
// 300MB/88us), so duration ~ traffic. BN=256 cuts A-rereads in half.
// Counted-vmcnt double-buffer (r3-proven): stage(t+1) -> vmcnt(3) waits only
// tile t (3 loads/thread/tile: 1 A-chunk + 2 B-chunks) -> barrier -> ds_read
// + MFMA -> lgkmcnt(0)+barrier (WAR guard).
// T2 chunk-XOR swizzle (r3-verified): src col-chunk ^= (row>>1)&3; fragment
// read chunk = quad ^ ((l15>>1)&3).
// ---------------------------------------------------------------------------
template <int MODE>
__global__ __launch_bounds__(512) void gemm_kernel(
    const bf16* __restrict__ A, const bf16* __restrict__ WT,
    const float* __restrict__ b0, const float* __restrict__ b1, const float* __restrict__ b2,
    int s1, int s2,
    void* __restrict__ o0, void* __restrict__ o1,
    int N, int K, int Kpart)
{
    __shared__ __align__(16) bf16 sA[2][128 * 32];
    __shared__ __align__(16) bf16 sB[2][256 * 32];

    const int tid  = threadIdx.x;
    const int lane = tid & 63;
    const int wave = tid >> 6;
    const int quad = lane >> 4;
    const int l15  = lane & 15;
    const int wm   = (wave >> 2) * 64;      // 0 | 64
    const int wn   = (wave & 3) * 64;       // 0 | 64 | 128 | 192

    int bxs, bys, bzs;
    xcd_swizzle(bxs, bys, bzs);
    const int bm = bys * 128;
    const int bn = bxs * 256;
    const int kbase = bzs * Kpart;

    f32x4 acc[4][4];
#pragma unroll
    for (int i = 0; i < 4; i++)
#pragma unroll
        for (int j = 0; j < 4; j++)
#pragma unroll
            for (int r = 0; r < 4; r++) acc[i][j][r] = 0.0f;

    // staging: A tile 128x32 = 512 chunks (1/thread); B tile 256x32 = 1024
    // chunks (2/thread). chunk c -> row c>>2, colchunk (c&3) ^ ((row>>1)&3).
    const int cA  = tid;
    const int rA  = cA >> 2,  kA  = (((cA  & 3) ^ ((rA  >> 1) & 3)) * 8);
    const int cB0 = tid;
    const int rB0 = cB0 >> 2, kB0 = (((cB0 & 3) ^ ((rB0 >> 1) & 3)) * 8);
    const int cB1 = tid + 512;
    const int rB1 = cB1 >> 2, kB1 = (((cB1 & 3) ^ ((rB1 >> 1) & 3)) * 8);

    const bf16* Arow  = A  + (size_t)(bm + rA)  * K + kbase + kA;
    const bf16* Brow0 = WT + (size_t)(bn + rB0) * K + kbase + kB0;
    const bf16* Brow1 = WT + (size_t)(bn + rB1) * K + kbase + kB1;

    const int nk = Kpart >> 5;

    // prologue: stage tile 0 into buffer 0
    async16(Arow,  sA[0] + cA  * 8);
    async16(Brow0, sB[0] + cB0 * 8);
    async16(Brow1, sB[0] + cB1 * 8);

    const int chF = (quad ^ ((l15 >> 1) & 3)) * 8;

    int cur = 0;
    for (int kt = 0; kt < nk; kt++) {
        if (kt + 1 < nk) {
            const int ko = (kt + 1) * 32;
            async16(Arow  + ko, sA[cur ^ 1] + cA  * 8);
            async16(Brow0 + ko, sB[cur ^ 1] + cB0 * 8);
            async16(Brow1 + ko, sB[cur ^ 1] + cB1 * 8);
            SYNC_VM(3);     // tile kt landed; kt+1's 3 loads stay in flight
        } else {
            SYNC_VM(0);
        }
        bf16x8 af[4], bfr[4];
#pragma unroll
        for (int i = 0; i < 4; i++)
            af[i] = *(const bf16x8*)(sA[cur] + (wm + i * 16 + l15) * 32 + chF);
#pragma unroll
        for (int i = 0; i < 4; i++)
            bfr[i] = *(const bf16x8*)(sB[cur] + (wn + i * 16 + l15) * 32 + chF);
#pragma unroll
        for (int mt = 0; mt < 4; mt++)
#pragma unroll
            for (int nt = 0; nt < 4; nt++)
                acc[mt][nt] = MFMA16(af[mt], bfr[nt], acc[mt][nt]);
        SYNC_LGKM();   // all waves' frag reads retired -> buf overwrite safe
        cur ^= 1;
    }

    void* outp = (bzs == 0) ? o0 : o1;

    // epilogue: C/D layout col = lane&15, row = quad*4 + r
#pragma unroll
    for (int nt = 0; nt < 4; nt++) {
        const int col = bn + wn + nt * 16 + l15;
        float bias = 0.0f;
        if (MODE != 1)
            bias = (col < s1) ? b0[col] : (col < s2) ? b1[col - s1] : b2[col - s2];
#pragma unroll
        for (int mt = 0; mt < 4; mt++) {
#pragma unroll
            for (int r = 0; r < 4; r++) {
                const int row = bm + wm + mt * 16 + quad * 4 + r;
                float v = acc[mt][nt][r] + bias;
                if (MODE == 2) v = 0.5f * v * (1.0f + erff(v * 0.70710678118654752f));
                if (MODE == 1) ((float*)outp)[(size_t)row * N + col] = v;
                else           ((bf16*)outp)[(size_t)row * N + col] = (bf16)v;
            }
        }
    }
}

// ---------------------------------------------------------------------------
// V-transpose: qkv V-part [key][dim] -> vT[bh][dim][key].
// ---------------------------------------------------------------------------
__global__ __launch_bounds__(256) void vtrans_kernel(
    const bf16* __restrict__ qkv, bf16* __restrict__ vT)
{
    const int bh = blockIdx.y;
    const int b = bh / 12, h = bh - b * 12;
    const int k0 = blockIdx.x * 128;
    __shared__ __align__(16) bf16 tile[128 * 72];
    const int tid = threadIdx.x;
    const bf16* src = qkv + (size_t)(b * 512 + k0) * 2304 + 1536 + h * 64;
#pragma unroll
    for (int i = 0; i < 4; i++) {
        const int idx = i * 256 + tid;
        const int r = idx >> 3, c = (idx & 7) * 8;
        *(uint4*)(tile + r * 72 + c) = *(const uint4*)(src + (size_t)r * 2304 + c);
    }
    __syncthreads();
    bf16* dst = vT + (size_t)bh * 64 * 512 + k0;
#pragma unroll
    for (int i = 0; i < 4; i++) {
        const int idx = i * 256 + tid;
        const int d = idx & 63, kg = idx >> 6;
        alignas(16) bf16 tmp[8];
#pragma unroll
        for (int e = 0; e < 8; e++) tmp[e] = tile[(kg * 8 + e) * 72 + d];
        *(uint4*)(dst + (size_t)d * 512 + kg * 8) = *(uint4*)tmp;
    }
}

// ---------------------------------------------------------------------------
// Attention (r3 structure, unchanged): counted-vmcnt K/V staging, XOR-swizzled
// tiles, Q in registers, V(0) stage hidden under softmax.
// ---------------------------------------------------------------------------
__global__ __launch_bounds__(256) void attn_kernel(
    const bf16* __restrict__ qkv, const bf16* __restrict__ vT,
    const float* __restrict__ mask, bf16* __restrict__ ctx)
{
    int bxs, bys, bzs;
    xcd_swizzle(bxs, bys, bzs);
    const int b = bzs, h = bys, q0 = bxs * 32;
    const int bh = b * 12 + h;
    const int tid = threadIdx.x, lane = tid & 63, wave = tid >> 6;
    const int quad = lane >> 4, l15 = lane & 15;
    const int mt = wave & 1;
    const int whi = wave >> 1;

    __shared__ __align__(16) bf16 sKV[2][64 * 64];
    __shared__ __align__(16) bf16 sS[32 * 520];
    __shared__ float sAM[512];
    __shared__ float sRed[256];
    __shared__ float sRow[32];

    for (int i = tid; i < 512; i += 256)
        sAM[i] = (1.0f - mask[b * 512 + i]) * -10000.0f;

    const size_t RS = 2304;
    const bf16* Qrow = qkv + (size_t)(b * 512 + q0 + mt * 16 + l15) * RS + h * 64;
    const bf16x8 aQ0 = *(const bf16x8*)(Qrow + quad * 8);
    const bf16x8 aQ1 = *(const bf16x8*)(Qrow + 32 + quad * 8);

    const int c0 = tid, c1 = tid + 256;
    const int r0 = c0 >> 3, r1 = c1 >> 3;
    const int sc0 = ((c0 & 7) ^ (r0 & 7)) * 8;
    const int sc1 = ((c1 & 7) ^ (r1 & 7)) * 8;

    const bf16* Kbase = qkv + (size_t)(b * 512) * RS + 768 + h * 64;

    async16(Kbase + (size_t)(r0) * RS + sc0, (bf16*)sKV[0] + c0 * 8);
    async16(Kbase + (size_t)(r1) * RS + sc1, (bf16*)sKV[0] + c1 * 8);

#pragma unroll
    for (int kt = 0; kt < 8; kt++) {
        const int cur = kt & 1;
        if (kt < 7) {
            async16(Kbase + (size_t)((kt + 1) * 64 + r0) * RS + sc0, (bf16*)sKV[cur ^ 1] + c0 * 8);
            async16(Kbase + (size_t)((kt + 1) * 64 + r1) * RS + sc1, (bf16*)sKV[cur ^ 1] + c1 * 8);
            SYNC_VM(2);
        } else {
            SYNC_VM(0);
        }
#pragma unroll
        for (int n = 0; n < 2; n++) {
            const int nt = whi * 2 + n;
            const int krow = nt * 16 + l15;
            const int sw = krow & 7;
            bf16x8 bK0 = *(const bf16x8*)(sKV[cur] + krow * 64 + ((quad ^ sw) * 8));
            bf16x8 bK1 = *(const bf16x8*)(sKV[cur] + krow * 64 + (((4 + quad) ^ sw) * 8));
            f32x4 accS;
#pragma unroll
            for (int r = 0; r < 4; r++) accS[r] = 0.0f;
            accS = MFMA16(aQ0, bK0, accS);
            accS = MFMA16(aQ1, bK1, accS);
#pragma unroll
            for (int r = 0; r < 4; r++) {
                const int row = mt * 16 + quad * 4 + r;
                sS[row * 520 + kt * 64 + nt * 16 + l15] = (bf16)accS[r];
            }
        }
        SYNC_LGKM();
    }

    const bf16* Vbase = vT + (size_t)bh * 64 * 512;
    async16(Vbase + (size_t)r0 * 512 + sc0, (bf16*)sKV[0] + c0 * 8);
    async16(Vbase + (size_t)r1 * 512 + sc1, (bf16*)sKV[0] + c1 * 8);

    {
        const int r = tid >> 3, p = tid & 7;
        float mx = -1e30f;
#pragma unroll
        for (int t = 0; t < 8; t++) {
            const int v0 = (p + 8 * t) * 8;
            bf16x8 pv = *(const bf16x8*)(sS + r * 520 + v0);
#pragma unroll
            for (int e = 0; e < 8; e++)
                mx = fmaxf(mx, (float)pv[e] * 0.125f + sAM[v0 + e]);
        }
        sRed[r * 8 + p] = mx;
        SYNC_LGKM();
#pragma unroll
        for (int q = 0; q < 8; q++) mx = fmaxf(mx, sRed[r * 8 + q]);
        float sum = 0.0f;
#pragma unroll
        for (int t = 0; t < 8; t++) {
            const int v0 = (p + 8 * t) * 8;
            bf16x8 pv = *(const bf16x8*)(sS + r * 520 + v0);
            bf16x8 ev;
#pragma unroll
            for (int e = 0; e < 8; e++) {
                const float x = __expf((float)pv[e] * 0.125f + sAM[v0 + e] - mx);
                sum += x;
                ev[e] = (bf16)x;
            }
            *(bf16x8*)(sS + r * 520 + v0) = ev;
        }
        SYNC_LGKM();
        sRed[r * 8 + p] = sum;
        SYNC_LGKM();
        if (p == 0) {
            float s = 0.0f;
#pragma unroll
            for (int q = 0; q < 8; q++) s += sRed[r * 8 + q];
            sRow[r] = s;
        }
    }

    f32x4 accO[2];
#pragma unroll
    for (int i = 0; i < 2; i++)
#pragma unroll
        for (int r = 0; r < 4; r++) accO[i][r] = 0.0f;

#pragma unroll
    for (int kt = 0; kt < 8; kt++) {
        const int cur = kt & 1;
        if (kt < 7) {
            async16(Vbase + (size_t)r0 * 512 + (kt + 1) * 64 + sc0, (bf16*)sKV[cur ^ 1] + c0 * 8);
            async16(Vbase + (size_t)r1 * 512 + (kt + 1) * 64 + sc1, (bf16*)sKV[cur ^ 1] + c1 * 8);
            SYNC_VM(2);
        } else {
            SYNC_VM(0);
        }
#pragma unroll
        for (int kk = 0; kk < 2; kk++) {
            bf16x8 aP = *(const bf16x8*)(sS + (mt * 16 + l15) * 520 + kt * 64 + kk * 32 + quad * 8);
#pragma unroll
            for (int n = 0; n < 2; n++) {
                const int vrow = whi * 32 + n * 16 + l15;
                bf16x8 bV = *(const bf16x8*)(sKV[cur] + vrow * 64 + (((kk * 4 + quad) ^ (vrow & 7)) * 8));
                accO[n] = MFMA16(aP, bV, accO[n]);
            }
        }
        SYNC_LGKM();
    }
#pragma unroll
    for (int n = 0; n < 2; n++) {
#pragma unroll
        for (int r = 0; r < 4; r++) {
            const int row = mt * 16 + quad * 4 + r;
            const float o = accO[n][r] / sRow[row];
            ctx[(size_t)(b * 512 + q0 + row) * 768 + h * 64 + whi * 32 + n * 16 + l15] = (bf16)o;
        }
    }
}

// ---------------------------------------------------------------------------
// Fused split-K reduce + bias + residual-add + LayerNorm.
// ---------------------------------------------------------------------------
template <int NP>
__global__ __launch_bounds__(256) void ln_kernel(
    const float* __restrict__ p0, const float* __restrict__ p1,
    const float* __restrict__ bias, const float* __restrict__ resid,
    const float* __restrict__ g, const float* __restrict__ bb,
    bf16* __restrict__ out_bf, float* __restrict__ out_f32)
{
    const int row = blockIdx.x;
    const int tid = threadIdx.x;
    __shared__ float sS[4], sQ[4];

    float x[3], s = 0.0f, sq = 0.0f;
#pragma unroll
    for (int j = 0; j < 3; j++) {
        const int c = tid + j * 256;
        const size_t idx = (size_t)row * 768 + c;
        float v = p0[idx] + bias[c] + resid[idx];
        if (NP > 1) v += p1[idx];
        x[j] = v; s += v; sq += v * v;
    }
#pragma unroll
    for (int off = 32; off; off >>= 1) { s += __shfl_down(s, off); sq += __shfl_down(sq, off); }
    if ((tid & 63) == 0) { sS[tid >> 6] = s; sQ[tid >> 6] = sq; }
    __syncthreads();
    s  = sS[0] + sS[1] + sS[2] + sS[3];
    sq = sQ[0] + sQ[1] + sQ[2] + sQ[3];
    const float mean = s * (1.0f / 768.0f);
    float var = sq * (1.0f / 768.0f) - mean * mean;
    var = fmaxf(var, 0.0f);
    const float rstd = rsqrtf(var + 1e-12f);
#pragma unroll
    for (int j = 0; j < 3; j++) {
        const int c = tid + j * 256;
        const float v = (x[j] - mean) * rstd * g[c] + bb[c];
        out_bf[(size_t)row * 768 + c] = (bf16)v;
        out_f32[(size_t)row * 768 + c] = v;
    }
}

// ---------------------------------------------------------------------------
// Transpose + quantize all 6 fp32 weight matrices of one layer into bf16 wT.
// ---------------------------------------------------------------------------
__global__ __launch_bounds__(256) void transpose_kernel(
    const float* __restrict__ Wq, const float* __restrict__ Wk, const float* __restrict__ Wv,
    const float* __restrict__ Wao, const float* __restrict__ Wi, const float* __restrict__ Wo,
    bf16* __restrict__ wT)
{
    __shared__ bf16 tile[64 * 68];
    int id = blockIdx.x;
    const float* src; bf16* dst; int Kd, Nd;
    if (id < 576) {
        const int w = id / 144; id -= w * 144;
        Kd = 768; Nd = 768;
        src = (w == 0) ? Wq : (w == 1) ? Wk : (w == 2) ? Wv : Wao;
        dst = wT + (size_t)w * 589824;
    } else if (id < 1152) {
        id -= 576; Kd = 768; Nd = 3072; src = Wi; dst = wT + 2359296;
    } else {
        id -= 1152; Kd = 3072; Nd = 768; src = Wo; dst = wT + 4718592;
    }
    const int tn = Nd >> 6;
    const int tr = id / tn, tc = id - tr * tn;
    const int r0 = tr * 64, c0 = tc * 64;
    const int tid = threadIdx.x;

#pragma unroll
    for (int i = 0; i < 4; i++) {
        const int idx = i * 256 + tid;
        const int r = idx >> 4, c4 = (idx & 15) * 4;
        const float4 f = *(const float4*)(src + (size_t)(r0 + r) * Nd + c0 + c4);
        alignas(8) bf16 q[4] = {(bf16)f.x, (bf16)f.y, (bf16)f.z, (bf16)f.w};
        *(ushort4*)(tile + r * 68 + c4) = *(ushort4*)q;
    }
    __syncthreads();
#pragma unroll
    for (int i = 0; i < 4; i++) {
        const int idx = i * 256 + tid;
        const int n = idx >> 4, kc = (idx & 15) * 4;
        alignas(8) bf16 tmp[4];
#pragma unroll
        for (int e = 0; e < 4; e++) tmp[e] = tile[(kc + e) * 68 + n];
        *(ushort4*)(dst + (size_t)(c0 + n) * Kd + r0 + kc) = *(ushort4*)tmp;
    }
}

__global__ __launch_bounds__(256) void convert_kernel(
    const float* __restrict__ in, bf16* __restrict__ out, int n)
{
    const int i = blockIdx.x * 256 + threadIdx.x;
    if (i < n) out[i] = (bf16)in[i];
}

// ---------------------------------------------------------------------------
extern "C" void kernel_launch(void* const* d_in, const int* in_sizes, int n_in,
                              void* d_out, int out_size, void* d_ws, size_t ws_size,
                              hipStream_t stream)
{
    const float* hidden = (const float*)d_in[0];
    const float* mask   = (const float*)d_in[1];
    const float* Wq  = (const float*)d_in[2];  const float* bq  = (const float*)d_in[3];
    const float* Wk  = (const float*)d_in[4];  const float* bk  = (const float*)d_in[5];
    const float* Wv  = (const float*)d_in[6];  const float* bv  = (const float*)d_in[7];
    const float* Wao = (const float*)d_in[8];  const float* bao = (const float*)d_in[9];
    const float* g1  = (const float*)d_in[10]; const float* be1 = (const float*)d_in[11];
    const float* Wi  = (const float*)d_in[12]; const float* bi  = (const float*)d_in[13];
    const float* Wo  = (const float*)d_in[14]; const float* bo  = (const float*)d_in[15];
    const float* g2  = (const float*)d_in[16]; const float* be2 = (const float*)d_in[17];

    // workspace layout (95,944,704 B) — identical to r3/r5 (lifetime-checked):
    //   wT    [0,          14155776)  bf16 weights (per layer)
    //   qkv   [14155776,   33030144)  bf16 4096x2304  (dead after attn)
    //   vT    [33030144,   39321600)  bf16            (dead after attn)
    //   ctx   [39321600,   45613056)  bf16            (dead after AO)
    //   attnb [45613056,   51904512)  bf16            (dead after FF1)
    //   xb    [51904512,   58195968)  bf16            (dead after QKV)
    //   xf    [58195968,   70778880)  f32 resid1      (dead after ln1)
    //   attnf [70778880,   83361792)  f32 resid2      (dead after ln2)
    //   spare [83361792,   95944704)  f32 12.58MB
    // partial aliases:
    //   AO (after attn, before ln1): pA0=qkv base, pA1=qkv+12.58MB
    //       (both inside [14155776,39321600), dead after attn). OK.
    //   ffh = [14155776, 39321600) FF1 out (clobbers pA* after ln1). OK.
    //   FF2: pF0=[39321600,51904512) (ctx+attnb, dead), pF1=spare. OK.
    char* ws = (char*)d_ws;
    bf16*  wT    = (bf16*)(ws);
    bf16*  qkv   = (bf16*)(ws + 14155776);
    bf16*  vT    = (bf16*)(ws + 33030144);
    bf16*  ctx   = (bf16*)(ws + 39321600);
    bf16*  attnb = (bf16*)(ws + 45613056);
    bf16*  xb    = (bf16*)(ws + 51904512);
    float* xf    = (float*)(ws + 58195968);
    float* attnf = (float*)(ws + 70778880);
    bf16*  ffh   = (bf16*)(ws + 14155776);
    float* pA0   = (float*)(ws + 14155776);
    float* pA1   = (float*)(ws + 26738688);
    float* pF0   = (float*)(ws + 39321600);
    float* pF1   = (float*)(ws + 83361792);

    convert_kernel<<<12288, 256, 0, stream>>>(hidden, xb, 3145728);

    for (int l = 0; l < 12; l++) {
        transpose_kernel<<<1728, 256, 0, stream>>>(
            Wq + (size_t)l * 589824, Wk + (size_t)l * 589824, Wv + (size_t)l * 589824,
            Wao + (size_t)l * 589824, Wi + (size_t)l * 2359296, Wo + (size_t)l * 2359296, wT);

        // QKV: M=4096 N=2304 K=768, BM=128/BN=256 -> 9x32 = 288 blocks
        gemm_kernel<0><<<dim3(9, 32, 1), 512, 0, stream>>>(
            xb, wT, bq + l * 768, bk + l * 768, bv + l * 768, 768, 1536,
            qkv, nullptr, 2304, 768, 768);

        vtrans_kernel<<<dim3(4, 96), 256, 0, stream>>>(qkv, vT);

        attn_kernel<<<dim3(16, 12, 8), 256, 0, stream>>>(qkv, vT, mask, ctx);

        // AO: M=4096 N=768 K=768, split-2 -> 3x32x2 = 192 blocks
        gemm_kernel<1><<<dim3(3, 32, 2), 512, 0, stream>>>(
            ctx, wT + 1769472, nullptr, nullptr, nullptr, 0, 0,
            pA0, pA1, 768, 768, 384);

        const float* resid1 = (l == 0) ? hidden : xf;
        ln_kernel<2><<<4096, 256, 0, stream>>>(
            pA0, pA1, bao + l * 768, resid1, g1 + l * 768, be1 + l * 768, attnb, attnf);

        // FF1: M=4096 N=3072 K=768 -> 12x32 = 384 blocks
        gemm_kernel<2><<<dim3(12, 32, 1), 512, 0, stream>>>(
            attnb, wT + 2359296, bi + l * 3072, bi + l * 3072, bi + l * 3072, 3072, 3072,
            ffh, nullptr, 3072, 768, 768);

        // FF2: M=4096 N=768 K=3072, split-2 -> 3x32x2 = 192 blocks
        gemm_kernel<1><<<dim3(3, 32, 2), 512, 0, stream>>>(
            ffh, wT + 4718592, nullptr, nullptr, nullptr, 0, 0,
            pF0, pF1, 768, 3072, 1536);

        float* f32dst = (l == 11) ? (float*)d_out : xf;
        ln_kernel<2><<<4096, 256, 0, stream>>>(
            pF0, pF1, bo + l * 768, attnf, g2 + l * 768, be2 + l * 768, xb, f32dst);
    }
}

// Round 7
// 2361.241 us; speedup vs baseline: 1.1853x; 1.0789x over previous
//
#include <hip/hip_runtime.h>
#include <hip/hip_bf16.h>

typedef __bf16 bf16;
typedef __attribute__((ext_vector_type(8))) __bf16 bf16x8;
typedef __attribute__((ext_vector_type(4))) float f32x4;

#define MFMA16(a, b, c) __builtin_amdgcn_mfma_f32_16x16x32_bf16((a), (b), (c), 0, 0, 0)

#define WAIT_VM(N) asm volatile("s_waitcnt vmcnt(" #N ")" ::: "memory")
#define BAR() do { __builtin_amdgcn_s_barrier(); __builtin_amdgcn_sched_barrier(0); } while (0)
#define SYNC_VM(N) do { WAIT_VM(N); BAR(); } while (0)
#define SYNC_LGKM() do { asm volatile("s_waitcnt lgkmcnt(0)" ::: "memory"); BAR(); } while (0)

__device__ __forceinline__ void async16(const bf16* g, bf16* l) {
    __builtin_amdgcn_global_load_lds((__attribute__((address_space(1))) void*)(g),
                                     (__attribute__((address_space(3))) void*)(l), 16, 0, 0);
}

// Bijective XCD-chunked swizzle (m204) over a 2D (gx,gy) grid slice.
__device__ __forceinline__ void xcd_swizzle2(int& bx, int& by) {
    const int gx = gridDim.x, gy = gridDim.y;
    const int nwg = gx * gy;
    const int lin = blockIdx.x + gx * blockIdx.y;
    const int xcd = lin & 7, seq = lin >> 3;
    const int q = nwg >> 3, r = nwg & 7;
    const int nl = (xcd < r ? xcd * (q + 1) : r * (q + 1) + (xcd - r) * q) + seq;
    bx = nl % gx;
    by = nl / gx;
}
// 3D variant for attention (unchanged from r3).
__device__ __forceinline__ void xcd_swizzle3(int& bx, int& by, int& bz) {
    const int gx = gridDim.x, gy = gridDim.y;
    const int nwg = gx * gy * gridDim.z;
    const int lin = blockIdx.x + gx * (blockIdx.y + gy * blockIdx.z);
    const int xcd = lin & 7, seq = lin >> 3;
    const int q = nwg >> 3, r = nwg & 7;
    const int nl = (xcd < r ? xcd * (q + 1) : r * (q + 1) + (xcd - r) * q) + seq;
    bx = nl % gx;
    const int t = nl / gx;
    by = t % gy;
    bz = t / gy;
}

// ---------------------------------------------------------------------------
// One 64x64 transpose+quantize tile of a layer's weight set.
// id in [0,1728): 0..575 = Wq/Wk/Wv/Wao (144 tiles each), 576..1151 = Wi,
// 1152..1727 = Wo. tile = 64*68 bf16 LDS scratch.
// ---------------------------------------------------------------------------
__device__ __forceinline__ void xpose_tile(
    int id, const float* Wq, const float* Wk, const float* Wv, const float* Wao,
    const float* Wi, const float* Wo, bf16* wT, bf16* tile, int tid)
{
    const float* src; bf16* dst; int Nd;
    if (id < 576) {
        const int w = id / 144; id -= w * 144;
        Nd = 768;
        src = (w == 0) ? Wq : (w == 1) ? Wk : (w == 2) ? Wv : Wao;
        dst = wT + (size_t)w * 589824;
    } else if (id < 1152) {
        id -= 576; Nd = 3072; src = Wi; dst = wT + 2359296;
    } else {
        id -= 1152; Nd = 768; src = Wo; dst = wT + 4718592;
    }
    const int Kd = (Nd == 3072) ? 768 : ((src == Wo) ? 3072 : 768);
    const int tn = Nd >> 6;
    const int tr = id / tn, tc = id - tr * tn;
    const int r0 = tr * 64, c0 = tc * 64;

#pragma unroll
    for (int i = 0; i < 4; i++) {
        const int idx = i * 256 + tid;
        const int r = idx >> 4, c4 = (idx & 15) * 4;
        const float4 f = *(const float4*)(src + (size_t)(r0 + r) * Nd + c0 + c4);
        alignas(8) bf16 q[4] = {(bf16)f.x, (bf16)f.y, (bf16)f.z, (bf16)f.w};
        *(ushort4*)(tile + r * 68 + c4) = *(ushort4*)q;
    }
    __syncthreads();
#pragma unroll
    for (int i = 0; i < 4; i++) {
        const int idx = i * 256 + tid;
        const int n = idx >> 4, kc = (idx & 15) * 4;
        alignas(8) bf16 tmp[4];
#pragma unroll
        for (int e = 0; e < 4; e++) tmp[e] = tile[(kc + e) * 68 + n];
        *(ushort4*)(dst + (size_t)(c0 + n) * Kd + r0 + kc) = *(ushort4*)tmp;
    }
}

// ---------------------------------------------------------------------------
// GEMM (exact r3 structure): C = A @ WT^T (+bias). BM in {64,128}, BN=128,
// BK=32, 256 thr = 4 waves 2x2; counted-vmcnt double buffer; T2 chunk-XOR.
// MODE 0 (QKV): bf16 out; cols < s2 -> qk[row*s2+col]; cols >= s2 (V) are
//   written DIRECTLY TRANSPOSED to vT[bh][d][key] (fuses the old vtrans).
// MODE 1: f32 partial, no bias (split-K<=2, reduced in ln).
// MODE 2: gelu(exact)+bias bf16 out.
// PACK=1: blockIdx.z==1 blocks instead run the weight transpose for the NEXT
//   layer's Wq..Wao (tiles 0..575) — overlapped, not serialized.
// ---------------------------------------------------------------------------
template <int MODE, int BM, int PACK>
__global__ __launch_bounds__(256) void gemm_kernel(
    const bf16* __restrict__ A, const bf16* __restrict__ WT,
    const float* __restrict__ b0, const float* __restrict__ b1, const float* __restrict__ b2,
    int s1, int s2,
    void* __restrict__ o0, void* __restrict__ o1, bf16* __restrict__ vTout,
    const float* __restrict__ xWq, const float* __restrict__ xWk,
    const float* __restrict__ xWv, const float* __restrict__ xWao,
    bf16* __restrict__ wTnext,
    int N, int K, int Kpart)
{
    constexpr int MT = BM / 32;
    constexpr int SBYTES = (2 * (BM * 32) + 2 * (128 * 32)) * 2;   // >= 8704
    __shared__ __align__(16) char smem[SBYTES];
    bf16* sA = (bf16*)smem;                       // [2][BM*32]
    bf16* sB = (bf16*)(smem + 2 * BM * 32 * 2);   // [2][128*32]

    const int tid = threadIdx.x;

    if (PACK && blockIdx.z == 1) {
        const int flat = blockIdx.y * gridDim.x + blockIdx.x;
        if (flat < 576 && wTnext)
            xpose_tile(flat, xWq, xWk, xWv, xWao, nullptr, nullptr, wTnext,
                       (bf16*)smem, tid);
        return;
    }
    const int kslice = PACK ? 0 : blockIdx.z;

    const int lane = tid & 63;
    const int wave = tid >> 6;
    const int quad = lane >> 4;
    const int l15  = lane & 15;
    const int wm   = (wave >> 1) * (BM / 2);
    const int wn   = (wave & 1) * 64;

    int bxs, bys;
    xcd_swizzle2(bxs, bys);
    const int bm = bys * BM;
    const int bn = bxs * 128;
    const int kbase = kslice * Kpart;

    f32x4 acc[MT][4];
#pragma unroll
    for (int i = 0; i < MT; i++)
#pragma unroll
        for (int j = 0; j < 4; j++)
#pragma unroll
            for (int r = 0; r < 4; r++) acc[i][j][r] = 0.0f;

    const int idx1 = tid + 256;
    const int ra0 = tid >> 2,  ca0 = (((tid  & 3) ^ ((ra0 >> 1) & 3)) * 8);
    const int rb1 = idx1 >> 2, cb1 = (((idx1 & 3) ^ ((rb1 >> 1) & 3)) * 8);

    const bf16* Arow0 = A + (size_t)(bm + ra0) * K + kbase + ca0;
    const bf16* Arow1 = (BM == 128) ? A + (size_t)(bm + rb1) * K + kbase + cb1 : A;
    const bf16* Brow0 = WT + (size_t)(bn + ra0) * K + kbase + ca0;
    const bf16* Brow1 = WT + (size_t)(bn + rb1) * K + kbase + cb1;

    const int nk = Kpart >> 5;

    async16(Arow0, sA + tid * 8);
    if (BM == 128) async16(Arow1, sA + idx1 * 8);
    async16(Brow0, sB + tid * 8);
    async16(Brow1, sB + idx1 * 8);

    const int chF = (quad ^ ((l15 >> 1) & 3)) * 8;

    int cur = 0;
    for (int kt = 0; kt < nk; kt++) {
        if (kt + 1 < nk) {
            const int ko = (kt + 1) * 32;
            const int nb = (cur ^ 1);
            async16(Arow0 + ko, sA + nb * BM * 32 + tid * 8);
            if (BM == 128) async16(Arow1 + ko, sA + nb * BM * 32 + idx1 * 8);
            async16(Brow0 + ko, sB + nb * 128 * 32 + tid * 8);
            async16(Brow1 + ko, sB + nb * 128 * 32 + idx1 * 8);
            if (BM == 128) SYNC_VM(4);
            else           SYNC_VM(3);
        } else {
            SYNC_VM(0);
        }
        const bf16* sAc = sA + cur * BM * 32;
        const bf16* sBc = sB + cur * 128 * 32;
        bf16x8 af[MT], bfr[4];
#pragma unroll
        for (int i = 0; i < MT; i++)
            af[i] = *(const bf16x8*)(sAc + (wm + i * 16 + l15) * 32 + chF);
#pragma unroll
        for (int i = 0; i < 4; i++)
            bfr[i] = *(const bf16x8*)(sBc + (wn + i * 16 + l15) * 32 + chF);
#pragma unroll
        for (int mt = 0; mt < MT; mt++)
#pragma unroll
            for (int nt = 0; nt < 4; nt++)
                acc[mt][nt] = MFMA16(af[mt], bfr[nt], acc[mt][nt]);
        SYNC_LGKM();
        cur ^= 1;
    }

    void* outp = (kslice == 0) ? o0 : o1;

#pragma unroll
    for (int nt = 0; nt < 4; nt++) {
        const int col = bn + wn + nt * 16 + l15;
        float bias = 0.0f;
        if (MODE != 1)
            bias = (col < s1) ? b0[col] : (col < s2) ? b1[col - s1] : b2[col - s2];
        if (MODE == 0 && col >= s2) {
            // V-part: write transposed into vT[bh][d][key] (fused vtrans).
            const int hd = col - s2, h = hd >> 6, d = hd & 63;
#pragma unroll
            for (int mt = 0; mt < MT; mt++) {
                const int row0 = bm + wm + mt * 16 + quad * 4;
                const int b = row0 >> 9, key = row0 & 511;
                alignas(8) bf16 tmp[4];
#pragma unroll
                for (int r = 0; r < 4; r++) tmp[r] = (bf16)(acc[mt][nt][r] + bias);
                *(ushort4*)(vTout + (((size_t)(b * 12 + h)) << 15) + (d << 9) + key)
                    = *(ushort4*)tmp;
            }
        } else {
#pragma unroll
            for (int mt = 0; mt < MT; mt++) {
#pragma unroll
                for (int r = 0; r < 4; r++) {
                    const int row = bm + wm + mt * 16 + quad * 4 + r;
                    float v = acc[mt][nt][r] + bias;
                    if (MODE == 2) v = 0.5f * v * (1.0f + erff(v * 0.70710678118654752f));
                    if (MODE == 1)      ((float*)outp)[(size_t)row * N + col] = v;
                    else if (MODE == 0) ((bf16*)outp)[(size_t)row * s2 + col] = (bf16)v;
                    else                ((bf16*)outp)[(size_t)row * N + col] = (bf16)v;
                }
            }
        }
    }
}

// ---------------------------------------------------------------------------
// Attention (r3 structure): counted-vmcnt K/V staging, XOR-swizzled tiles,
// Q in registers, V(0) stage hidden under softmax. Reads compact qk
// (stride 1536: Q at h*64, K at 768+h*64) and vT from the fused QKV.
// ---------------------------------------------------------------------------
__global__ __launch_bounds__(256) void attn_kernel(
    const bf16* __restrict__ qk, const bf16* __restrict__ vT,
    const float* __restrict__ mask, bf16* __restrict__ ctx)
{
    int bxs, bys, bzs;
    xcd_swizzle3(bxs, bys, bzs);
    const int b = bzs, h = bys, q0 = bxs * 32;
    const int bh = b * 12 + h;
    const int tid = threadIdx.x, lane = tid & 63, wave = tid >> 6;
    const int quad = lane >> 4, l15 = lane & 15;
    const int mt = wave & 1;
    const int whi = wave >> 1;

    __shared__ __align__(16) bf16 sKV[2][64 * 64];
    __shared__ __align__(16) bf16 sS[32 * 520];
    __shared__ float sAM[512];
    __shared__ float sRed[256];
    __shared__ float sRow[32];

    for (int i = tid; i < 512; i += 256)
        sAM[i] = (1.0f - mask[b * 512 + i]) * -10000.0f;

    const size_t RS = 1536;
    const bf16* Qrow = qk + (size_t)(b * 512 + q0 + mt * 16 + l15) * RS + h * 64;
    const bf16x8 aQ0 = *(const bf16x8*)(Qrow + quad * 8);
    const bf16x8 aQ1 = *(const bf16x8*)(Qrow + 32 + quad * 8);

    const int c0 = tid, c1 = tid + 256;
    const int r0 = c0 >> 3, r1 = c1 >> 3;
    const int sc0 = ((c0 & 7) ^ (r0 & 7)) * 8;
    const int sc1 = ((c1 & 7) ^ (r1 & 7)) * 8;

    const bf16* Kbase = qk + (size_t)(b * 512) * RS + 768 + h * 64;

    async16(Kbase + (size_t)(r0) * RS + sc0, (bf16*)sKV[0] + c0 * 8);
    async16(Kbase + (size_t)(r1) * RS + sc1, (bf16*)sKV[0] + c1 * 8);

#pragma unroll
    for (int kt = 0; kt < 8; kt++) {
        const int cur = kt & 1;
        if (kt < 7) {
            async16(Kbase + (size_t)((kt + 1) * 64 + r0) * RS + sc0, (bf16*)sKV[cur ^ 1] + c0 * 8);
            async16(Kbase + (size_t)((kt + 1) * 64 + r1) * RS + sc1, (bf16*)sKV[cur ^ 1] + c1 * 8);
            SYNC_VM(2);
        } else {
            SYNC_VM(0);
        }
#pragma unroll
        for (int n = 0; n < 2; n++) {
            const int nt = whi * 2 + n;
            const int krow = nt * 16 + l15;
            const int sw = krow & 7;
            bf16x8 bK0 = *(const bf16x8*)(sKV[cur] + krow * 64 + ((quad ^ sw) * 8));
            bf16x8 bK1 = *(const bf16x8*)(sKV[cur] + krow * 64 + (((4 + quad) ^ sw) * 8));
            f32x4 accS;
#pragma unroll
            for (int r = 0; r < 4; r++) accS[r] = 0.0f;
            accS = MFMA16(aQ0, bK0, accS);
            accS = MFMA16(aQ1, bK1, accS);
#pragma unroll
            for (int r = 0; r < 4; r++) {
                const int row = mt * 16 + quad * 4 + r;
                sS[row * 520 + kt * 64 + nt * 16 + l15] = (bf16)accS[r];
            }
        }
        SYNC_LGKM();
    }

    const bf16* Vbase = vT + (size_t)bh * 64 * 512;
    async16(Vbase + (size_t)r0 * 512 + sc0, (bf16*)sKV[0] + c0 * 8);
    async16(Vbase + (size_t)r1 * 512 + sc1, (bf16*)sKV[0] + c1 * 8);

    {
        const int r = tid >> 3, p = tid & 7;
        float mx = -1e30f;
#pragma unroll
        for (int t = 0; t < 8; t++) {
            const int v0 = (p + 8 * t) * 8;
            bf16x8 pv = *(const bf16x8*)(sS + r * 520 + v0);
#pragma unroll
            for (int e = 0; e < 8; e++)
                mx = fmaxf(mx, (float)pv[e] * 0.125f + sAM[v0 + e]);
        }
        sRed[r * 8 + p] = mx;
        SYNC_LGKM();
#pragma unroll
        for (int q = 0; q < 8; q++) mx = fmaxf(mx, sRed[r * 8 + q]);
        float sum = 0.0f;
#pragma unroll
        for (int t = 0; t < 8; t++) {
            const int v0 = (p + 8 * t) * 8;
            bf16x8 pv = *(const bf16x8*)(sS + r * 520 + v0);
            bf16x8 ev;
#pragma unroll
            for (int e = 0; e < 8; e++) {
                const float x = __expf((float)pv[e] * 0.125f + sAM[v0 + e] - mx);
                sum += x;
                ev[e] = (bf16)x;
            }
            *(bf16x8*)(sS + r * 520 + v0) = ev;
        }
        SYNC_LGKM();
        sRed[r * 8 + p] = sum;
        SYNC_LGKM();
        if (p == 0) {
            float s = 0.0f;
#pragma unroll
            for (int q = 0; q < 8; q++) s += sRed[r * 8 + q];
            sRow[r] = s;
        }
    }

    f32x4 accO[2];
#pragma unroll
    for (int i = 0; i < 2; i++)
#pragma unroll
        for (int r = 0; r < 4; r++) accO[i][r] = 0.0f;

#pragma unroll
    for (int kt = 0; kt < 8; kt++) {
        const int cur = kt & 1;
        if (kt < 7) {
            async16(Vbase + (size_t)r0 * 512 + (kt + 1) * 64 + sc0, (bf16*)sKV[cur ^ 1] + c0 * 8);
            async16(Vbase + (size_t)r1 * 512 + (kt + 1) * 64 + sc1, (bf16*)sKV[cur ^ 1] + c1 * 8);
            SYNC_VM(2);
        } else {
            SYNC_VM(0);
        }
#pragma unroll
        for (int kk = 0; kk < 2; kk++) {
            bf16x8 aP = *(const bf16x8*)(sS + (mt * 16 + l15) * 520 + kt * 64 + kk * 32 + quad * 8);
#pragma unroll
            for (int n = 0; n < 2; n++) {
                const int vrow = whi * 32 + n * 16 + l15;
                bf16x8 bV = *(const bf16x8*)(sKV[cur] + vrow * 64 + (((kk * 4 + quad) ^ (vrow & 7)) * 8));
                accO[n] = MFMA16(aP, bV, accO[n]);
            }
        }
        SYNC_LGKM();
    }
#pragma unroll
    for (int n = 0; n < 2; n++) {
#pragma unroll
        for (int r = 0; r < 4; r++) {
            const int row = mt * 16 + quad * 4 + r;
            const float o = accO[n][r] / sRow[row];
            ctx[(size_t)(b * 512 + q0 + row) * 768 + h * 64 + whi * 32 + n * 16 + l15] = (bf16)o;
        }
    }
}

// ---------------------------------------------------------------------------
// Fused split-K reduce + bias + residual-add + LayerNorm.
// PACK=1: blocks >= 4096 run the next layer's Wi/Wo transpose (tiles 576..1727).
// NO __restrict__ on p/out: p1 may exactly overlay out_f32 (same-index,
// per-thread read-before-write, rows block-exclusive -> safe; r4-proven).
// ---------------------------------------------------------------------------
template <int NP, int PACK>
__global__ __launch_bounds__(256) void ln_kernel(
    const float* p0, const float* p1,
    const float* bias, const float* resid,
    const float* g, const float* bb,
    bf16* out_bf, float* out_f32,
    const float* xWi, const float* xWo, bf16* wTnext)
{
    if constexpr (PACK) {
        __shared__ __align__(16) bf16 xtile[64 * 68];
        if (blockIdx.x >= 4096) {
            if (wTnext)
                xpose_tile(576 + (blockIdx.x - 4096), nullptr, nullptr, nullptr,
                           nullptr, xWi, xWo, wTnext, xtile, threadIdx.x);
            return;
        }
    }
    const int row = blockIdx.x;
    const int tid = threadIdx.x;
    __shared__ float sS[4], sQ[4];

    float x[3], s = 0.0f, sq = 0.0f;
#pragma unroll
    for (int j = 0; j < 3; j++) {
        const int c = tid + j * 256;
        const size_t idx = (size_t)row * 768 + c;
        float v = p0[idx] + bias[c] + resid[idx];
        if (NP > 1) v += p1[idx];
        x[j] = v; s += v; sq += v * v;
    }
#pragma unroll
    for (int off = 32; off; off >>= 1) { s += __shfl_down(s, off); sq += __shfl_down(sq, off); }
    if ((tid & 63) == 0) { sS[tid >> 6] = s; sQ[tid >> 6] = sq; }
    __syncthreads();
    s  = sS[0] + sS[1] + sS[2] + sS[3];
    sq = sQ[0] + sQ[1] + sQ[2] + sQ[3];
    const float mean = s * (1.0f / 768.0f);
    float var = sq * (1.0f / 768.0f) - mean * mean;
    var = fmaxf(var, 0.0f);
    const float rstd = rsqrtf(var + 1e-12f);
#pragma unroll
    for (int j = 0; j < 3; j++) {
        const int c = tid + j * 256;
        const float v = (x[j] - mean) * rstd * g[c] + bb[c];
        out_bf[(size_t)row * 768 + c] = (bf16)v;
        out_f32[(size_t)row * 768 + c] = v;
    }
}

// ---------------------------------------------------------------------------
// Prep: input fp32->bf16 convert (blocks 0..12287) packed with the full
// weight transpose of layer 0 (blocks 12288..14015).
// ---------------------------------------------------------------------------
__global__ __launch_bounds__(256) void prep_kernel(
    const float* __restrict__ hidden, bf16* __restrict__ xb,
    const float* __restrict__ Wq, const float* __restrict__ Wk,
    const float* __restrict__ Wv, const float* __restrict__ Wao,
    const float* __restrict__ Wi, const float* __restrict__ Wo,
    bf16* __restrict__ wT)
{
    __shared__ __align__(16) bf16 tile[64 * 68];
    if (blockIdx.x < 12288) {
        const int i = blockIdx.x * 256 + threadIdx.x;
        if (i < 3145728) xb[i] = (bf16)hidden[i];
        return;
    }
    xpose_tile(blockIdx.x - 12288, Wq, Wk, Wv, Wao, Wi, Wo, wT, tile, threadIdx.x);
}

// ---------------------------------------------------------------------------
extern "C" void kernel_launch(void* const* d_in, const int* in_sizes, int n_in,
                              void* d_out, int out_size, void* d_ws, size_t ws_size,
                              hipStream_t stream)
{
    const float* hidden = (const float*)d_in[0];
    const float* mask   = (const float*)d_in[1];
    const float* Wq  = (const float*)d_in[2];  const float* bq  = (const float*)d_in[3];
    const float* Wk  = (const float*)d_in[4];  const float* bk  = (const float*)d_in[5];
    const float* Wv  = (const float*)d_in[6];  const float* bv  = (const float*)d_in[7];
    const float* Wao = (const float*)d_in[8];  const float* bao = (const float*)d_in[9];
    const float* g1  = (const float*)d_in[10]; const float* be1 = (const float*)d_in[11];
    const float* Wi  = (const float*)d_in[12]; const float* bi  = (const float*)d_in[13];
    const float* Wo  = (const float*)d_in[14]; const float* bo  = (const float*)d_in[15];
    const float* g2  = (const float*)d_in[16]; const float* be2 = (const float*)d_in[17];

    // workspace layout (91,226,112 B used of >=95,944,704):
    //   wT    [0,        14155776)  bf16, single buffer; per-region overwrite
    //         schedule: Wq..Wao(l+1) written during FF1(l) (after AO(l) read
    //         them); Wi/Wo(l+1) written during ln2(l) (after FF1/FF2(l)).
    //   qk    [14155776, 26738688)  bf16 4096x1536 (Q|K; dead after attn)
    //   vT    [26738688, 33030144)  bf16 (written by QKV, dead after attn)
    //   ctx   [33030144, 39321600)  bf16 (dead after AO)
    //   attnb [39321600, 45613056)  bf16 (dead after FF1)
    //   xb    [45613056, 51904512)  bf16 (dead after QKV)
    //   xf    [51904512, 64487424)  f32 resid1 (dead after ln1)
    //   attnf [64487424, 77070336)  f32 resid2 (dead after ln2)
    //   free  [77070336, 95944704)
    // aliases (lifetime-checked):
    //   ffh = qk+vT+ctx [14155776, 39321600) = 4096x3072 bf16 exactly (FF1 out)
    //   pA0 = qk region (dead after attn), pA1 = free region
    //   pF0 = free region, pF1 = xf (dead after ln1; ln2 out_f32==pF1 at l<11
    //         is the r4-proven same-index overlay)
    char* ws = (char*)d_ws;
    bf16*  wT    = (bf16*)(ws);
    bf16*  qk    = (bf16*)(ws + 14155776);
    bf16*  vT    = (bf16*)(ws + 26738688);
    bf16*  ctx   = (bf16*)(ws + 33030144);
    bf16*  attnb = (bf16*)(ws + 39321600);
    bf16*  xb    = (bf16*)(ws + 45613056);
    float* xf    = (float*)(ws + 51904512);
    float* attnf = (float*)(ws + 64487424);
    bf16*  ffh   = (bf16*)(ws + 14155776);
    float* pA0   = (float*)(ws + 14155776);
    float* pA1   = (float*)(ws + 77070336);
    float* pF0   = (float*)(ws + 77070336);
    float* pF1   = (float*)(ws + 51904512);

    prep_kernel<<<14016, 256, 0, stream>>>(hidden, xb, Wq, Wk, Wv, Wao, Wi, Wo, wT);

    for (int l = 0; l < 12; l++) {
        const int ln = l + 1;
        bf16* wTn = (l < 11) ? wT : nullptr;

        // QKV (+fused V-transpose): M=4096 N=2304 K=768, BM=64 -> 1152 blocks
        gemm_kernel<0, 64, 0><<<dim3(18, 64, 1), 256, 0, stream>>>(
            xb, wT, bq + l * 768, bk + l * 768, bv + l * 768, 768, 1536,
            qk, nullptr, vT, nullptr, nullptr, nullptr, nullptr, nullptr,
            2304, 768, 768);

        attn_kernel<<<dim3(16, 12, 8), 256, 0, stream>>>(qk, vT, mask, ctx);

        // AO: M=4096 N=768 K=768, BM=64 split-2 -> 768 blocks
        gemm_kernel<1, 64, 0><<<dim3(6, 64, 2), 256, 0, stream>>>(
            ctx, wT + 1769472, nullptr, nullptr, nullptr, 0, 0,
            pA0, pA1, nullptr, nullptr, nullptr, nullptr, nullptr, nullptr,
            768, 768, 384);

        const float* resid1 = (l == 0) ? hidden : xf;
        ln_kernel<2, 0><<<4096, 256, 0, stream>>>(
            pA0, pA1, bao + l * 768, resid1, g1 + l * 768, be1 + l * 768,
            attnb, attnf, nullptr, nullptr, nullptr);

        // FF1 (+packed transpose of next layer's Wq..Wao): BM=128 -> 768+768 blocks
        gemm_kernel<2, 128, 1><<<dim3(24, 32, 2), 256, 0, stream>>>(
            attnb, wT + 2359296, bi + l * 3072, bi + l * 3072, bi + l * 3072, 3072, 3072,
            ffh, nullptr, nullptr,
            Wq + (size_t)(ln % 12) * 589824, Wk + (size_t)(ln % 12) * 589824,
            Wv + (size_t)(ln % 12) * 589824, Wao + (size_t)(ln % 12) * 589824, wTn,
            3072, 768, 768);

        // FF2: M=4096 N=768 K=3072, BM=64 split-2 -> 768 blocks
        gemm_kernel<1, 64, 0><<<dim3(6, 64, 2), 256, 0, stream>>>(
            ffh, wT + 4718592, nullptr, nullptr, nullptr, 0, 0,
            pF0, pF1, nullptr, nullptr, nullptr, nullptr, nullptr, nullptr,
            768, 3072, 1536);

        // ln2 (+packed transpose of next layer's Wi/Wo): 4096+1152 blocks
        float* f32dst = (l == 11) ? (float*)d_out : xf;
        ln_kernel<2, 1><<<4096 + 1152, 256, 0, stream>>>(
            pF0, pF1, bo + l * 768, attnf, g2 + l * 768, be2 + l * 768,
            xb, f32dst,
            Wi + (size_t)(ln % 12) * 2359296, Wo + (size_t)(ln % 12) * 2359296, wTn);
    }
}

// Round 8
// 2239.089 us; speedup vs baseline: 1.2499x; 1.0546x over previous
//
#include <hip/hip_runtime.h>
#include <hip/hip_bf16.h>

typedef __bf16 bf16;
typedef __attribute__((ext_vector_type(8))) __bf16 bf16x8;
typedef __attribute__((ext_vector_type(4))) float f32x4;

#define MFMA16(a, b, c) __builtin_amdgcn_mfma_f32_16x16x32_bf16((a), (b), (c), 0, 0, 0)

#define WAIT_VM(N) asm volatile("s_waitcnt vmcnt(" #N ")" ::: "memory")
#define BAR() do { __builtin_amdgcn_s_barrier(); __builtin_amdgcn_sched_barrier(0); } while (0)
#define SYNC_VM(N) do { WAIT_VM(N); BAR(); } while (0)
#define SYNC_LGKM() do { asm volatile("s_waitcnt lgkmcnt(0)" ::: "memory"); BAR(); } while (0)

__device__ __forceinline__ void async16(const bf16* g, bf16* l) {
    __builtin_amdgcn_global_load_lds((__attribute__((address_space(1))) void*)(g),
                                     (__attribute__((address_space(3))) void*)(l), 16, 0, 0);
}

// Bijective XCD-chunked swizzle (m204) over the (x,y) plane of the grid.
__device__ __forceinline__ void xcd_swizzle2(int& bx, int& by) {
    const int gx = gridDim.x, gy = gridDim.y;
    const int nwg = gx * gy;
    const int lin = blockIdx.x + gx * blockIdx.y;
    const int xcd = lin & 7, seq = lin >> 3;
    const int q = nwg >> 3, r = nwg & 7;
    const int nl = (xcd < r ? xcd * (q + 1) : r * (q + 1) + (xcd - r) * q) + seq;
    bx = nl % gx;
    by = nl / gx;
}
__device__ __forceinline__ void xcd_swizzle3(int& bx, int& by, int& bz) {
    const int gx = gridDim.x, gy = gridDim.y;
    const int nwg = gx * gy * gridDim.z;
    const int lin = blockIdx.x + gx * (blockIdx.y + gy * blockIdx.z);
    const int xcd = lin & 7, seq = lin >> 3;
    const int q = nwg >> 3, r = nwg & 7;
    const int nl = (xcd < r ? xcd * (q + 1) : r * (q + 1) + (xcd - r) * q) + seq;
    bx = nl % gx;
    const int t = nl / gx;
    by = t % gy;
    bz = t / gy;
}

// ---------------------------------------------------------------------------
// One 64x64 transpose+quantize tile of a layer's weight set.
// id: 0..575 = Wq/Wk/Wv/Wao (144 each), 576..1151 = Wi, 1152..1727 = Wo.
// ---------------------------------------------------------------------------
__device__ __forceinline__ void xpose_tile(
    int id, const float* Wq, const float* Wk, const float* Wv, const float* Wao,
    const float* Wi, const float* Wo, bf16* wT, bf16* tile, int tid)
{
    const float* src; bf16* dst; int Nd, Kd;
    if (id < 576) {
        const int w = id / 144; id -= w * 144;
        Nd = 768; Kd = 768;
        src = (w == 0) ? Wq : (w == 1) ? Wk : (w == 2) ? Wv : Wao;
        dst = wT + (size_t)w * 589824;
    } else if (id < 1152) {
        id -= 576; Nd = 3072; Kd = 768; src = Wi; dst = wT + 2359296;
    } else {
        id -= 1152; Nd = 768; Kd = 3072; src = Wo; dst = wT + 4718592;
    }
    const int tn = Nd >> 6;
    const int tr = id / tn, tc = id - tr * tn;
    const int r0 = tr * 64, c0 = tc * 64;

#pragma unroll
    for (int i = 0; i < 4; i++) {
        const int idx = i * 256 + tid;
        const int r = idx >> 4, c4 = (idx & 15) * 4;
        const float4 f = *(const float4*)(src + (size_t)(r0 + r) * Nd + c0 + c4);
        alignas(8) bf16 q[4] = {(bf16)f.x, (bf16)f.y, (bf16)f.z, (bf16)f.w};
        *(ushort4*)(tile + r * 68 + c4) = *(ushort4*)q;
    }
    __syncthreads();
#pragma unroll
    for (int i = 0; i < 4; i++) {
        const int idx = i * 256 + tid;
        const int n = idx >> 4, kc = (idx & 15) * 4;
        alignas(8) bf16 tmp[4];
#pragma unroll
        for (int e = 0; e < 4; e++) tmp[e] = tile[(kc + e) * 68 + n];
        *(ushort4*)(dst + (size_t)(c0 + n) * Kd + r0 + kc) = *(ushort4*)tmp;
    }
}

// ---------------------------------------------------------------------------
// GEMM, BK=64: C = A @ WT^T (+bias). BM=64, BN=128, 256 thr = 4 waves 2x2,
// each wave a 32x64 sub-tile (2x4 frags, K in 2 halves -> 16 MFMA/iter).
// WHY BK=64: per-iteration sync overhead (stage+vmcnt+barrier pair) measured
// ~72% of critical path (m233 signature: MfmaUtil 8.5 / VALU 17 / 75% idle);
// halving nk at CONSTANT occupancy (48KB LDS -> still 3 blocks/CU, avoiding
// the m132 BK=128 occupancy trap) cuts time ~0.64x.
// Staging: A tile 64x64 = 512 chunks (2/thr), B tile 128x64 = 1024 (4/thr);
// 6 global_load_lds/thr/iter, steady vmcnt(6) (tile kt landed, kt+1 in
// flight). 8-chunk row-XOR swizzle (r3-attn-verified): src chunk
// (c&7)^(row&7), read chunk (kk*4+quad)^(l15&7) -> conflict-free.
// MODE 0 (QKV): bf16 out to qk[row*s2+col]; V-cols written transposed to vT.
// MODE 1: f32 partial (split-K<=2). MODE 2: gelu(exact)+bias bf16.
// ---------------------------------------------------------------------------
template <int MODE>
__global__ __launch_bounds__(256) void gemm_kernel(
    const bf16* __restrict__ A, const bf16* __restrict__ WT,
    const float* __restrict__ b0, const float* __restrict__ b1, const float* __restrict__ b2,
    int s1, int s2,
    void* __restrict__ o0, void* __restrict__ o1, bf16* __restrict__ vTout,
    int N, int K, int Kpart)
{
    __shared__ __align__(16) bf16 sA[2][64 * 64];    // 16 KB
    __shared__ __align__(16) bf16 sB[2][128 * 64];   // 32 KB

    const int tid  = threadIdx.x;
    const int lane = tid & 63;
    const int wave = tid >> 6;
    const int quad = lane >> 4;
    const int l15  = lane & 15;
    const int wm   = (wave >> 1) * 32;
    const int wn   = (wave & 1) * 64;

    int bxs, bys;
    xcd_swizzle2(bxs, bys);
    const int bm = bys * 64;
    const int bn = bxs * 128;
    const int kbase = blockIdx.z * Kpart;

    f32x4 acc[2][4];
#pragma unroll
    for (int i = 0; i < 2; i++)
#pragma unroll
        for (int j = 0; j < 4; j++)
#pragma unroll
            for (int r = 0; r < 4; r++) acc[i][j][r] = 0.0f;

    // staging chunks (16B): row = c>>3, src col-chunk = ((c&7) ^ (row&7))*8
    const int cA0 = tid,       cA1 = tid + 256;
    const int cB0 = tid,       cB1 = tid + 256;
    const int cB2 = tid + 512, cB3 = tid + 768;
    const int rA0 = cA0 >> 3, kA0 = (((cA0 & 7) ^ (rA0 & 7)) * 8);
    const int rA1 = cA1 >> 3, kA1 = (((cA1 & 7) ^ (rA1 & 7)) * 8);
    const int rB0 = cB0 >> 3, kB0 = (((cB0 & 7) ^ (rB0 & 7)) * 8);
    const int rB1 = cB1 >> 3, kB1 = (((cB1 & 7) ^ (rB1 & 7)) * 8);
    const int rB2 = cB2 >> 3, kB2 = (((cB2 & 7) ^ (rB2 & 7)) * 8);
    const int rB3 = cB3 >> 3, kB3 = (((cB3 & 7) ^ (rB3 & 7)) * 8);

    const bf16* A0 = A  + (size_t)(bm + rA0) * K + kbase + kA0;
    const bf16* A1 = A  + (size_t)(bm + rA1) * K + kbase + kA1;
    const bf16* B0 = WT + (size_t)(bn + rB0) * K + kbase + kB0;
    const bf16* B1 = WT + (size_t)(bn + rB1) * K + kbase + kB1;
    const bf16* B2 = WT + (size_t)(bn + rB2) * K + kbase + kB2;
    const bf16* B3 = WT + (size_t)(bn + rB3) * K + kbase + kB3;

    const int nk = Kpart >> 6;

    auto stage = [&](int kt, int buf) {
        const int ko = kt * 64;
        async16(A0 + ko, sA[buf] + cA0 * 8);
        async16(A1 + ko, sA[buf] + cA1 * 8);
        async16(B0 + ko, sB[buf] + cB0 * 8);
        async16(B1 + ko, sB[buf] + cB1 * 8);
        async16(B2 + ko, sB[buf] + cB2 * 8);
        async16(B3 + ko, sB[buf] + cB3 * 8);
    };

    stage(0, 0);

    const int xr = (l15 & 7);   // per-lane read XOR (row&7 == l15&7 for frag rows)

    int cur = 0;
    for (int kt = 0; kt < nk; kt++) {
        if (kt + 1 < nk) {
            stage(kt + 1, cur ^ 1);
            SYNC_VM(6);          // tile kt landed; kt+1's 6 loads in flight
        } else {
            SYNC_VM(0);
        }
        bf16x8 af[2][2], bfr[4][2];
#pragma unroll
        for (int kk = 0; kk < 2; kk++) {
            const int ch = ((kk * 4 + quad) ^ xr) * 8;
#pragma unroll
            for (int i = 0; i < 2; i++)
                af[i][kk] = *(const bf16x8*)(sA[cur] + (wm + i * 16 + l15) * 64 + ch);
#pragma unroll
            for (int i = 0; i < 4; i++)
                bfr[i][kk] = *(const bf16x8*)(sB[cur] + (wn + i * 16 + l15) * 64 + ch);
        }
#pragma unroll
        for (int mt = 0; mt < 2; mt++)
#pragma unroll
            for (int nt = 0; nt < 4; nt++)
#pragma unroll
                for (int kk = 0; kk < 2; kk++)
                    acc[mt][nt] = MFMA16(af[mt][kk], bfr[nt][kk], acc[mt][nt]);
        SYNC_LGKM();   // all waves' frag reads retired -> buf overwrite safe
        cur ^= 1;
    }

    void* outp = (blockIdx.z == 0) ? o0 : o1;

#pragma unroll
    for (int nt = 0; nt < 4; nt++) {
        const int col = bn + wn + nt * 16 + l15;
        float bias = 0.0f;
        if (MODE != 1)
            bias = (col < s1) ? b0[col] : (col < s2) ? b1[col - s1] : b2[col - s2];
        if (MODE == 0 && col >= s2) {
            // V-part: write transposed into vT[bh][d][key] (fused vtrans).
            const int hd = col - s2, h = hd >> 6, d = hd & 63;
#pragma unroll
            for (int mt = 0; mt < 2; mt++) {
                const int row0 = bm + wm + mt * 16 + quad * 4;
                const int b = row0 >> 9, key = row0 & 511;
                alignas(8) bf16 tmp[4];
#pragma unroll
                for (int r = 0; r < 4; r++) tmp[r] = (bf16)(acc[mt][nt][r] + bias);
                *(ushort4*)(vTout + (((size_t)(b * 12 + h)) << 15) + (d << 9) + key)
                    = *(ushort4*)tmp;
            }
        } else {
#pragma unroll
            for (int mt = 0; mt < 2; mt++) {
#pragma unroll
                for (int r = 0; r < 4; r++) {
                    const int row = bm + wm + mt * 16 + quad * 4 + r;
                    float v = acc[mt][nt][r] + bias;
                    if (MODE == 2) v = 0.5f * v * (1.0f + erff(v * 0.70710678118654752f));
                    if (MODE == 1)      ((float*)outp)[(size_t)row * N + col] = v;
                    else if (MODE == 0) ((bf16*)outp)[(size_t)row * s2 + col] = (bf16)v;
                    else                ((bf16*)outp)[(size_t)row * N + col] = (bf16)v;
                }
            }
        }
    }
}

// ---------------------------------------------------------------------------
// Attention (r3/r7 structure, unchanged): counted-vmcnt K/V staging, XOR
// swizzle, Q in registers, V(0) stage hidden under softmax. Reads compact qk
// (stride 1536) and vT.
// ---------------------------------------------------------------------------
__global__ __launch_bounds__(256) void attn_kernel(
    const bf16* __restrict__ qk, const bf16* __restrict__ vT,
    const float* __restrict__ mask, bf16* __restrict__ ctx)
{
    int bxs, bys, bzs;
    xcd_swizzle3(bxs, bys, bzs);
    const int b = bzs, h = bys, q0 = bxs * 32;
    const int bh = b * 12 + h;
    const int tid = threadIdx.x, lane = tid & 63, wave = tid >> 6;
    const int quad = lane >> 4, l15 = lane & 15;
    const int mt = wave & 1;
    const int whi = wave >> 1;

    __shared__ __align__(16) bf16 sKV[2][64 * 64];
    __shared__ __align__(16) bf16 sS[32 * 520];
    __shared__ float sAM[512];
    __shared__ float sRed[256];
    __shared__ float sRow[32];

    for (int i = tid; i < 512; i += 256)
        sAM[i] = (1.0f - mask[b * 512 + i]) * -10000.0f;

    const size_t RS = 1536;
    const bf16* Qrow = qk + (size_t)(b * 512 + q0 + mt * 16 + l15) * RS + h * 64;
    const bf16x8 aQ0 = *(const bf16x8*)(Qrow + quad * 8);
    const bf16x8 aQ1 = *(const bf16x8*)(Qrow + 32 + quad * 8);

    const int c0 = tid, c1 = tid + 256;
    const int r0 = c0 >> 3, r1 = c1 >> 3;
    const int sc0 = ((c0 & 7) ^ (r0 & 7)) * 8;
    const int sc1 = ((c1 & 7) ^ (r1 & 7)) * 8;

    const bf16* Kbase = qk + (size_t)(b * 512) * RS + 768 + h * 64;

    async16(Kbase + (size_t)(r0) * RS + sc0, (bf16*)sKV[0] + c0 * 8);
    async16(Kbase + (size_t)(r1) * RS + sc1, (bf16*)sKV[0] + c1 * 8);

#pragma unroll
    for (int kt = 0; kt < 8; kt++) {
        const int cur = kt & 1;
        if (kt < 7) {
            async16(Kbase + (size_t)((kt + 1) * 64 + r0) * RS + sc0, (bf16*)sKV[cur ^ 1] + c0 * 8);
            async16(Kbase + (size_t)((kt + 1) * 64 + r1) * RS + sc1, (bf16*)sKV[cur ^ 1] + c1 * 8);
            SYNC_VM(2);
        } else {
            SYNC_VM(0);
        }
#pragma unroll
        for (int n = 0; n < 2; n++) {
            const int nt = whi * 2 + n;
            const int krow = nt * 16 + l15;
            const int sw = krow & 7;
            bf16x8 bK0 = *(const bf16x8*)(sKV[cur] + krow * 64 + ((quad ^ sw) * 8));
            bf16x8 bK1 = *(const bf16x8*)(sKV[cur] + krow * 64 + (((4 + quad) ^ sw) * 8));
            f32x4 accS;
#pragma unroll
            for (int r = 0; r < 4; r++) accS[r] = 0.0f;
            accS = MFMA16(aQ0, bK0, accS);
            accS = MFMA16(aQ1, bK1, accS);
#pragma unroll
            for (int r = 0; r < 4; r++) {
                const int row = mt * 16 + quad * 4 + r;
                sS[row * 520 + kt * 64 + nt * 16 + l15] = (bf16)accS[r];
            }
        }
        SYNC_LGKM();
    }

    const bf16* Vbase = vT + (size_t)bh * 64 * 512;
    async16(Vbase + (size_t)r0 * 512 + sc0, (bf16*)sKV[0] + c0 * 8);
    async16(Vbase + (size_t)r1 * 512 + sc1, (bf16*)sKV[0] + c1 * 8);

    {
        const int r = tid >> 3, p = tid & 7;
        float mx = -1e30f;
#pragma unroll
        for (int t = 0; t < 8; t++) {
            const int v0 = (p + 8 * t) * 8;
            bf16x8 pv = *(const bf16x8*)(sS + r * 520 + v0);
#pragma unroll
            for (int e = 0; e < 8; e++)
                mx = fmaxf(mx, (float)pv[e] * 0.125f + sAM[v0 + e]);
        }
        sRed[r * 8 + p] = mx;
        SYNC_LGKM();
#pragma unroll
        for (int q = 0; q < 8; q++) mx = fmaxf(mx, sRed[r * 8 + q]);
        float sum = 0.0f;
#pragma unroll
        for (int t = 0; t < 8; t++) {
            const int v0 = (p + 8 * t) * 8;
            bf16x8 pv = *(const bf16x8*)(sS + r * 520 + v0);
            bf16x8 ev;
#pragma unroll
            for (int e = 0; e < 8; e++) {
                const float x = __expf((float)pv[e] * 0.125f + sAM[v0 + e] - mx);
                sum += x;
                ev[e] = (bf16)x;
            }
            *(bf16x8*)(sS + r * 520 + v0) = ev;
        }
        SYNC_LGKM();
        sRed[r * 8 + p] = sum;
        SYNC_LGKM();
        if (p == 0) {
            float s = 0.0f;
#pragma unroll
            for (int q = 0; q < 8; q++) s += sRed[r * 8 + q];
            sRow[r] = s;
        }
    }

    f32x4 accO[2];
#pragma unroll
    for (int i = 0; i < 2; i++)
#pragma unroll
        for (int r = 0; r < 4; r++) accO[i][r] = 0.0f;

#pragma unroll
    for (int kt = 0; kt < 8; kt++) {
        const int cur = kt & 1;
        if (kt < 7) {
            async16(Vbase + (size_t)r0 * 512 + (kt + 1) * 64 + sc0, (bf16*)sKV[cur ^ 1] + c0 * 8);
            async16(Vbase + (size_t)r1 * 512 + (kt + 1) * 64 + sc1, (bf16*)sKV[cur ^ 1] + c1 * 8);
            SYNC_VM(2);
        } else {
            SYNC_VM(0);
        }
#pragma unroll
        for (int kk = 0; kk < 2; kk++) {
            bf16x8 aP = *(const bf16x8*)(sS + (mt * 16 + l15) * 520 + kt * 64 + kk * 32 + quad * 8);
#pragma unroll
            for (int n = 0; n < 2; n++) {
                const int vrow = whi * 32 + n * 16 + l15;
                bf16x8 bV = *(const bf16x8*)(sKV[cur] + vrow * 64 + (((kk * 4 + quad) ^ (vrow & 7)) * 8));
                accO[n] = MFMA16(aP, bV, accO[n]);
            }
        }
        SYNC_LGKM();
    }
#pragma unroll
    for (int n = 0; n < 2; n++) {
#pragma unroll
        for (int r = 0; r < 4; r++) {
            const int row = mt * 16 + quad * 4 + r;
            const float o = accO[n][r] / sRow[row];
            ctx[(size_t)(b * 512 + q0 + row) * 768 + h * 64 + whi * 32 + n * 16 + l15] = (bf16)o;
        }
    }
}

// ---------------------------------------------------------------------------
// Fused split-K reduce + bias + residual-add + LayerNorm.
// PACKSEL 1: blocks >= 4096 transpose next layer's Wq..Wao (ids 0..575).
// PACKSEL 2: blocks >= 4096 transpose next layer's Wi/Wo (ids 576..1727).
// NO __restrict__: p1 may overlay out_f32 (same-index, read-before-write,
// rows block-exclusive -> safe; r4-proven).
// ---------------------------------------------------------------------------
template <int NP, int PACKSEL>
__global__ __launch_bounds__(256) void ln_kernel(
    const float* p0, const float* p1,
    const float* bias, const float* resid,
    const float* g, const float* bb,
    bf16* out_bf, float* out_f32,
    const float* xW0, const float* xW1, const float* xW2, const float* xW3,
    bf16* wTnext)
{
    if constexpr (PACKSEL > 0) {
        if (blockIdx.x >= 4096) {
            __shared__ __align__(16) bf16 xtile[64 * 68];
            if (wTnext) {
                if (PACKSEL == 1)
                    xpose_tile(blockIdx.x - 4096, xW0, xW1, xW2, xW3,
                               nullptr, nullptr, wTnext, xtile, threadIdx.x);
                else
                    xpose_tile(576 + (blockIdx.x - 4096), nullptr, nullptr, nullptr,
                               nullptr, xW0, xW1, wTnext, xtile, threadIdx.x);
            }
            return;
        }
    }
    const int row = blockIdx.x;
    const int tid = threadIdx.x;
    __shared__ float sS[4], sQ[4];

    float x[3], s = 0.0f, sq = 0.0f;
#pragma unroll
    for (int j = 0; j < 3; j++) {
        const int c = tid + j * 256;
        const size_t idx = (size_t)row * 768 + c;
        float v = p0[idx] + bias[c] + resid[idx];
        if (NP > 1) v += p1[idx];
        x[j] = v; s += v; sq += v * v;
    }
#pragma unroll
    for (int off = 32; off; off >>= 1) { s += __shfl_down(s, off); sq += __shfl_down(sq, off); }
    if ((tid & 63) == 0) { sS[tid >> 6] = s; sQ[tid >> 6] = sq; }
    __syncthreads();
    s  = sS[0] + sS[1] + sS[2] + sS[3];
    sq = sQ[0] + sQ[1] + sQ[2] + sQ[3];
    const float mean = s * (1.0f / 768.0f);
    float var = sq * (1.0f / 768.0f) - mean * mean;
    var = fmaxf(var, 0.0f);
    const float rstd = rsqrtf(var + 1e-12f);
#pragma unroll
    for (int j = 0; j < 3; j++) {
        const int c = tid + j * 256;
        const float v = (x[j] - mean) * rstd * g[c] + bb[c];
        out_bf[(size_t)row * 768 + c] = (bf16)v;
        out_f32[(size_t)row * 768 + c] = v;
    }
}

// ---------------------------------------------------------------------------
// Prep: input fp32->bf16 convert (blocks 0..12287) + full layer-0 weight
// transpose (blocks 12288..14015).
// ---------------------------------------------------------------------------
__global__ __launch_bounds__(256) void prep_kernel(
    const float* __restrict__ hidden, bf16* __restrict__ xb,
    const float* __restrict__ Wq, const float* __restrict__ Wk,
    const float* __restrict__ Wv, const float* __restrict__ Wao,
    const float* __restrict__ Wi, const float* __restrict__ Wo,
    bf16* __restrict__ wT)
{
    __shared__ __align__(16) bf16 tile[64 * 68];
    if (blockIdx.x < 12288) {
        const int i = blockIdx.x * 256 + threadIdx.x;
        if (i < 3145728) xb[i] = (bf16)hidden[i];
        return;
    }
    xpose_tile(blockIdx.x - 12288, Wq, Wk, Wv, Wao, Wi, Wo, wT, tile, threadIdx.x);
}

// ---------------------------------------------------------------------------
extern "C" void kernel_launch(void* const* d_in, const int* in_sizes, int n_in,
                              void* d_out, int out_size, void* d_ws, size_t ws_size,
                              hipStream_t stream)
{
    const float* hidden = (const float*)d_in[0];
    const float* mask   = (const float*)d_in[1];
    const float* Wq  = (const float*)d_in[2];  const float* bq  = (const float*)d_in[3];
    const float* Wk  = (const float*)d_in[4];  const float* bk  = (const float*)d_in[5];
    const float* Wv  = (const float*)d_in[6];  const float* bv  = (const float*)d_in[7];
    const float* Wao = (const float*)d_in[8];  const float* bao = (const float*)d_in[9];
    const float* g1  = (const float*)d_in[10]; const float* be1 = (const float*)d_in[11];
    const float* Wi  = (const float*)d_in[12]; const float* bi  = (const float*)d_in[13];
    const float* Wo  = (const float*)d_in[14]; const float* bo  = (const float*)d_in[15];
    const float* g2  = (const float*)d_in[16]; const float* be2 = (const float*)d_in[17];

    // workspace layout (r7-identical, lifetime-checked):
    //   wT    [0,        14155776)  bf16 single buffer; overwrite schedule:
    //         Wq..Wao(l+1) written during ln1(l) (AO(l) read them already);
    //         Wi/Wo(l+1) written during ln2(l) (FF1/FF2(l) done).
    //   qk    [14155776, 26738688)  bf16 4096x1536 (dead after attn)
    //   vT    [26738688, 33030144)  bf16 (dead after attn)
    //   ctx   [33030144, 39321600)  bf16 (dead after AO)
    //   attnb [39321600, 45613056)  bf16 (dead after FF1)
    //   xb    [45613056, 51904512)  bf16 (dead after QKV)
    //   xf    [51904512, 64487424)  f32 resid1 (dead after ln1)
    //   attnf [64487424, 77070336)  f32 resid2 (dead after ln2)
    //   free  [77070336, 95944704)
    // aliases: ffh = qk+vT+ctx (FF1 out, 4096x3072 bf16 exactly);
    //   pA0 = qk region (dead after attn), pA1 = free;
    //   pF0 = free, pF1 = xf (ln2 out_f32==pF1 at l<11: r4-proven overlay).
    char* ws = (char*)d_ws;
    bf16*  wT    = (bf16*)(ws);
    bf16*  qk    = (bf16*)(ws + 14155776);
    bf16*  vT    = (bf16*)(ws + 26738688);
    bf16*  ctx   = (bf16*)(ws + 33030144);
    bf16*  attnb = (bf16*)(ws + 39321600);
    bf16*  xb    = (bf16*)(ws + 45613056);
    float* xf    = (float*)(ws + 51904512);
    float* attnf = (float*)(ws + 64487424);
    bf16*  ffh   = (bf16*)(ws + 14155776);
    float* pA0   = (float*)(ws + 14155776);
    float* pA1   = (float*)(ws + 77070336);
    float* pF0   = (float*)(ws + 77070336);
    float* pF1   = (float*)(ws + 51904512);

    prep_kernel<<<14016, 256, 0, stream>>>(hidden, xb, Wq, Wk, Wv, Wao, Wi, Wo, wT);

    for (int l = 0; l < 12; l++) {
        const int ln = (l + 1) % 12;
        bf16* wTn = (l < 11) ? wT : nullptr;

        // QKV (+fused V-transpose): M=4096 N=2304 K=768 -> 18x64 = 1152 blocks, nk=12
        gemm_kernel<0><<<dim3(18, 64, 1), 256, 0, stream>>>(
            xb, wT, bq + l * 768, bk + l * 768, bv + l * 768, 768, 1536,
            qk, nullptr, vT, 2304, 768, 768);

        attn_kernel<<<dim3(16, 12, 8), 256, 0, stream>>>(qk, vT, mask, ctx);

        // AO: M=4096 N=768 K=768 split-2 -> 6x64x2 = 768 blocks, nk=6
        gemm_kernel<1><<<dim3(6, 64, 2), 256, 0, stream>>>(
            ctx, wT + 1769472, nullptr, nullptr, nullptr, 0, 0,
            pA0, pA1, nullptr, 768, 768, 384);

        // ln1 (+packed transpose of next layer's Wq..Wao): 4096+576 blocks
        const float* resid1 = (l == 0) ? hidden : xf;
        ln_kernel<2, 1><<<4096 + 576, 256, 0, stream>>>(
            pA0, pA1, bao + l * 768, resid1, g1 + l * 768, be1 + l * 768,
            attnb, attnf,
            Wq + (size_t)ln * 589824, Wk + (size_t)ln * 589824,
            Wv + (size_t)ln * 589824, Wao + (size_t)ln * 589824, wTn);

        // FF1: M=4096 N=3072 K=768 -> 24x64 = 1536 blocks, nk=12
        gemm_kernel<2><<<dim3(24, 64, 1), 256, 0, stream>>>(
            attnb, wT + 2359296, bi + l * 3072, bi + l * 3072, bi + l * 3072, 3072, 3072,
            ffh, nullptr, nullptr, 3072, 768, 768);

        // FF2: M=4096 N=768 K=3072 split-2 -> 6x64x2 = 768 blocks, nk=24
        gemm_kernel<1><<<dim3(6, 64, 2), 256, 0, stream>>>(
            ffh, wT + 4718592, nullptr, nullptr, nullptr, 0, 0,
            pF0, pF1, nullptr, 768, 3072, 1536);

        // ln2 (+packed transpose of next layer's Wi/Wo): 4096+1152 blocks
        float* f32dst = (l == 11) ? (float*)d_out : xf;
        ln_kernel<2, 2><<<4096 + 1152, 256, 0, stream>>>(
            pF0, pF1, bo + l * 768, attnf, g2 + l * 768, be2 + l * 768,
            xb, f32dst,
            Wi + (size_t)ln * 2359296, Wo + (size_t)ln * 2359296, nullptr, nullptr, wTn);
    }
}